// Round 1
// baseline (1559.820 us; speedup 1.0000x reference)
//
#include <hip/hip_runtime.h>
#include <hip/hip_bf16.h>

// ---------------------------------------------------------------------------
// GatedNetwork: N = 131072 nodes == edges, C = 256 channels.
// Pipeline:
//   P_h = h @ [A|B|V|U]^T + bias   (bf16 MFMA GEMM, tiled-layout inputs)
//   P_e = e @ [C|D]^T + bias
//   e_out[k] = HA[row]+HB[col]+EC[col]+ED[row]   (+ batch stats)
//   BN+ReLU -> scatter-add into acc=e -> sigmoid -> colsum-normalize = e_new
//   T[c] = sum_k e_new[k][c]*HV[col[k]][c];  h_out = relu(HU + T)
// ---------------------------------------------------------------------------

typedef __attribute__((ext_vector_type(8))) short bf16x8;
typedef __attribute__((ext_vector_type(4))) float f32x4;

__device__ __forceinline__ float b2f(unsigned int lo16) {
  union { unsigned int u; float f; } c; c.u = lo16 << 16; return c.f;
}
__device__ __forceinline__ float lof(unsigned int u) { return b2f(u & 0xffffu); }
__device__ __forceinline__ float hif(unsigned int u) { return b2f(u >> 16); }
__device__ __forceinline__ unsigned int f2b(float f) {  // RNE f32->bf16
  union { float f; unsigned int u; } c; c.f = f;
  unsigned int u = c.u;
  u += 0x7fffu + ((u >> 16) & 1u);
  return u >> 16;
}

// --- prep: f32 row-major [M][256] -> bf16 tiled [M/16][32][16][8] ----------
__global__ __launch_bounds__(256) void prep_tiled(const float* __restrict__ src,
                                                  unsigned short* __restrict__ dst,
                                                  int nChunks) {
  int g = blockIdx.x * 256 + threadIdx.x;
  if (g >= nChunks) return;
  int mtile = g >> 9;
  int rem = g & 511;
  int r = rem >> 5, k8 = rem & 31;
  const float4* s = reinterpret_cast<const float4*>(src + (((size_t)mtile * 16 + r) << 8) + k8 * 8);
  float4 v0 = s[0], v1 = s[1];
  uint4 o;
  o.x = f2b(v0.x) | (f2b(v0.y) << 16);
  o.y = f2b(v0.z) | (f2b(v0.w) << 16);
  o.z = f2b(v1.x) | (f2b(v1.y) << 16);
  o.w = f2b(v1.z) | (f2b(v1.w) << 16);
  *reinterpret_cast<uint4*>(dst + ((size_t)mtile * 512 + k8 * 16 + r) * 8) = o;
}

// --- GEMM: C[m][o] = sum_k A[m][k]*B[o][k] + bias[o], bf16 in, bf16 out ----
// A,B in tiled layout. 256 thr = 4 waves, 128x128 tile, BK=32, K=256 fixed.
__global__ __launch_bounds__(256) void gemm_bt(const unsigned short* __restrict__ At,
                                               const unsigned short* __restrict__ Bt,
                                               const float* __restrict__ bias,
                                               unsigned short* __restrict__ Cmat,
                                               int O, int nColBlk) {
  __shared__ char lds[16384];  // A: [0,8K), B: [8K,16K), fragment-order slots
  const int bid = blockIdx.x;
  const int colBlk = bid % nColBlk;
  const int rowBlk = bid / nColBlk;
  const int tid = threadIdx.x;
  const int w = tid >> 6, lane = tid & 63;
  const int wm = w >> 1, wn = w & 1;

  const char* Abase = (const char*)At + (size_t)(rowBlk * 8 + w * 2) * 8192 + lane * 16;
  const char* Bbase = (const char*)Bt + (size_t)(colBlk * 8 + w * 2) * 8192 + lane * 16;
  char* ldsA0 = lds + (w * 2) * 1024;
  char* ldsA1 = lds + (w * 2 + 1) * 1024;
  char* ldsB0 = lds + 8192 + (w * 2) * 1024;
  char* ldsB1 = lds + 8192 + (w * 2 + 1) * 1024;

  f32x4 acc[4][4] = {};

  for (int kt = 0; kt < 8; ++kt) {
    const size_t ko = (size_t)kt * 1024;
    __builtin_amdgcn_global_load_lds((const __attribute__((address_space(1))) void*)(Abase + ko),
                                     (__attribute__((address_space(3))) void*)ldsA0, 16, 0, 0);
    __builtin_amdgcn_global_load_lds((const __attribute__((address_space(1))) void*)(Abase + 8192 + ko),
                                     (__attribute__((address_space(3))) void*)ldsA1, 16, 0, 0);
    __builtin_amdgcn_global_load_lds((const __attribute__((address_space(1))) void*)(Bbase + ko),
                                     (__attribute__((address_space(3))) void*)ldsB0, 16, 0, 0);
    __builtin_amdgcn_global_load_lds((const __attribute__((address_space(1))) void*)(Bbase + 8192 + ko),
                                     (__attribute__((address_space(3))) void*)ldsB1, 16, 0, 0);
    __syncthreads();  // drains vmcnt(0): LDS tiles ready
    bf16x8 a[4], b[4];
#pragma unroll
    for (int mi = 0; mi < 4; ++mi)
      a[mi] = *reinterpret_cast<const bf16x8*>(lds + (wm * 4 + mi) * 1024 + lane * 16);
#pragma unroll
    for (int ni = 0; ni < 4; ++ni)
      b[ni] = *reinterpret_cast<const bf16x8*>(lds + 8192 + (wn * 4 + ni) * 1024 + lane * 16);
#pragma unroll
    for (int mi = 0; mi < 4; ++mi)
#pragma unroll
      for (int ni = 0; ni < 4; ++ni)
        acc[mi][ni] = __builtin_amdgcn_mfma_f32_16x16x32_bf16(a[mi], b[ni], acc[mi][ni], 0, 0, 0);
    __syncthreads();  // compute done before next stage overwrites
  }

  const int rb = rowBlk * 128 + wm * 64 + ((lane >> 4) << 2);
  const int cb = colBlk * 128 + wn * 64 + (lane & 15);
#pragma unroll
  for (int mi = 0; mi < 4; ++mi) {
#pragma unroll
    for (int ni = 0; ni < 4; ++ni) {
      const int coln = cb + ni * 16;
      const float bz = bias[coln];
      const size_t base = (size_t)(rb + mi * 16) * O + coln;
#pragma unroll
      for (int r = 0; r < 4; ++r)
        Cmat[base + (size_t)r * O] = (unsigned short)f2b(acc[mi][ni][r] + bz);
    }
  }
}

// --- edge_sum: e_out[k] = HA[row]+HB[col]+EC[col]+ED[row]; accumulate stats -
__global__ __launch_bounds__(256) void edge_sum(
    const unsigned short* __restrict__ Ph, const unsigned short* __restrict__ Pe,
    const int* __restrict__ ei, const int* __restrict__ modep,
    unsigned short* __restrict__ eout,
    float* __restrict__ sums, float* __restrict__ sumsq, int Nn) {
  __shared__ float red[8][256];
  const int c8 = threadIdx.x & 31;
  const int sub = threadIdx.x >> 5;
  const int mode = *modep;
  float s[8], q[8];
#pragma unroll
  for (int j = 0; j < 8; ++j) { s[j] = 0.f; q[j] = 0.f; }

#pragma unroll 1
  for (int it = 0; it < 8; ++it) {
    const int k = blockIdx.x * 64 + it * 8 + sub;
    int row, col;
    if (mode) { row = ei[2 * k]; col = ei[2 * (Nn + k)]; }
    else      { row = ei[k];     col = ei[Nn + k]; }
    const uint4 ha = *reinterpret_cast<const uint4*>(Ph + (size_t)row * 1024 + c8 * 8);
    const uint4 hb = *reinterpret_cast<const uint4*>(Ph + (size_t)col * 1024 + 256 + c8 * 8);
    const uint4 ec = *reinterpret_cast<const uint4*>(Pe + (size_t)col * 512 + c8 * 8);
    const uint4 ed = *reinterpret_cast<const uint4*>(Pe + (size_t)row * 512 + 256 + c8 * 8);
    const unsigned int aw[4] = {ha.x, ha.y, ha.z, ha.w};
    const unsigned int bw[4] = {hb.x, hb.y, hb.z, hb.w};
    const unsigned int cw[4] = {ec.x, ec.y, ec.z, ec.w};
    const unsigned int dw[4] = {ed.x, ed.y, ed.z, ed.w};
    unsigned int ow[4];
#pragma unroll
    for (int p = 0; p < 4; ++p) {
      float v0 = lof(aw[p]) + lof(bw[p]) + lof(cw[p]) + lof(dw[p]);
      float v1 = hif(aw[p]) + hif(bw[p]) + hif(cw[p]) + hif(dw[p]);
      s[2 * p] += v0;     q[2 * p] += v0 * v0;
      s[2 * p + 1] += v1; q[2 * p + 1] += v1 * v1;
      ow[p] = f2b(v0) | (f2b(v1) << 16);
    }
    uint4 o; o.x = ow[0]; o.y = ow[1]; o.z = ow[2]; o.w = ow[3];
    *reinterpret_cast<uint4*>(eout + (size_t)k * 256 + c8 * 8) = o;
  }
#pragma unroll
  for (int j = 0; j < 8; ++j) red[sub][c8 * 8 + j] = s[j];
  __syncthreads();
  {
    const int c = threadIdx.x;
    float t = 0.f;
#pragma unroll
    for (int u2 = 0; u2 < 8; ++u2) t += red[u2][c];
    atomicAdd(sums + c, t);
  }
  __syncthreads();
#pragma unroll
  for (int j = 0; j < 8; ++j) red[sub][c8 * 8 + j] = q[j];
  __syncthreads();
  {
    const int c = threadIdx.x;
    float t = 0.f;
#pragma unroll
    for (int u2 = 0; u2 < 8; ++u2) t += red[u2][c];
    atomicAdd(sumsq + c, t);
  }
}

__global__ void bn_finalize(const float* __restrict__ sums, const float* __restrict__ sumsq,
                            const float* __restrict__ gamma, const float* __restrict__ beta,
                            float* __restrict__ scale, float* __restrict__ shift, float invE) {
  const int c = threadIdx.x;
  const float mu = sums[c] * invE;
  const float var = fmaxf(sumsq[c] * invE - mu * mu, 0.f);
  const float sc = gamma[c] * rsqrtf(var + 1e-5f);
  scale[c] = sc;
  shift[c] = beta[c] - mu * sc;
}

__global__ __launch_bounds__(256) void scatter_relu(
    const unsigned short* __restrict__ eout, const int* __restrict__ ei,
    const int* __restrict__ modep,
    const float* __restrict__ scale, const float* __restrict__ shift,
    float* __restrict__ acc, int Nn) {
  const int c8 = threadIdx.x & 31, sub = threadIdx.x >> 5;
  const int mode = *modep;
  float sc[8], sh[8];
#pragma unroll
  for (int j = 0; j < 8; ++j) { sc[j] = scale[c8 * 8 + j]; sh[j] = shift[c8 * 8 + j]; }
#pragma unroll 1
  for (int it = 0; it < 8; ++it) {
    const int k = blockIdx.x * 64 + it * 8 + sub;
    const int row = mode ? ei[2 * k] : ei[k];
    const uint4 eo = *reinterpret_cast<const uint4*>(eout + (size_t)k * 256 + c8 * 8);
    const unsigned int w4[4] = {eo.x, eo.y, eo.z, eo.w};
    float* dst = acc + (size_t)row * 256 + c8 * 8;
#pragma unroll
    for (int p = 0; p < 4; ++p) {
      const float y0 = fmaxf(fmaf(sc[2 * p], lof(w4[p]), sh[2 * p]), 0.f);
      const float y1 = fmaxf(fmaf(sc[2 * p + 1], hif(w4[p]), sh[2 * p + 1]), 0.f);
      atomicAdd(dst + 2 * p, y0);
      atomicAdd(dst + 2 * p + 1, y1);
    }
  }
}

__global__ __launch_bounds__(256) void sigmoid_colsum(float* __restrict__ acc,
                                                      float* __restrict__ colsum) {
  __shared__ float red[8][256];
  const int c8 = threadIdx.x & 31, sub = threadIdx.x >> 5;
  float s[8];
#pragma unroll
  for (int j = 0; j < 8; ++j) s[j] = 0.f;
#pragma unroll 1
  for (int it = 0; it < 8; ++it) {
    const int i = blockIdx.x * 64 + it * 8 + sub;
    float4* p0 = reinterpret_cast<float4*>(acc + (size_t)i * 256 + c8 * 8);
    float4 a = p0[0], b = p0[1];
    float v[8] = {a.x, a.y, a.z, a.w, b.x, b.y, b.z, b.w};
#pragma unroll
    for (int j = 0; j < 8; ++j) { v[j] = 1.f / (1.f + __expf(-v[j])); s[j] += v[j]; }
    a.x = v[0]; a.y = v[1]; a.z = v[2]; a.w = v[3];
    b.x = v[4]; b.y = v[5]; b.z = v[6]; b.w = v[7];
    p0[0] = a; p0[1] = b;
  }
#pragma unroll
  for (int j = 0; j < 8; ++j) red[sub][c8 * 8 + j] = s[j];
  __syncthreads();
  {
    const int c = threadIdx.x;
    float t = 0.f;
#pragma unroll
    for (int u2 = 0; u2 < 8; ++u2) t += red[u2][c];
    atomicAdd(colsum + c, t);
  }
}

__global__ void inv_finalize(const float* __restrict__ colsum, float* __restrict__ inv) {
  const int c = threadIdx.x;
  inv[c] = 1.0f / (colsum[c] + 1e-5f);
}

__global__ __launch_bounds__(256) void enew_T(
    const float* __restrict__ acc, const float* __restrict__ inv,
    const int* __restrict__ ei, const int* __restrict__ modep,
    const unsigned short* __restrict__ Ph,
    float* __restrict__ outE, float* __restrict__ T, int Nn) {
  __shared__ float red[8][256];
  const int c8 = threadIdx.x & 31, sub = threadIdx.x >> 5;
  const int mode = *modep;
  float iv[8];
#pragma unroll
  for (int j = 0; j < 8; ++j) iv[j] = inv[c8 * 8 + j];
  float t[8];
#pragma unroll
  for (int j = 0; j < 8; ++j) t[j] = 0.f;
#pragma unroll 1
  for (int it = 0; it < 8; ++it) {
    const int k = blockIdx.x * 64 + it * 8 + sub;
    const int col = mode ? ei[2 * (Nn + k)] : ei[Nn + k];
    const float4* p0 = reinterpret_cast<const float4*>(acc + (size_t)k * 256 + c8 * 8);
    const float4 a = p0[0], b = p0[1];
    float en[8] = {a.x * iv[0], a.y * iv[1], a.z * iv[2], a.w * iv[3],
                   b.x * iv[4], b.y * iv[5], b.z * iv[6], b.w * iv[7]};
    float4 o0, o1;
    o0.x = en[0]; o0.y = en[1]; o0.z = en[2]; o0.w = en[3];
    o1.x = en[4]; o1.y = en[5]; o1.z = en[6]; o1.w = en[7];
    float4* q0 = reinterpret_cast<float4*>(outE + (size_t)k * 256 + c8 * 8);
    q0[0] = o0; q0[1] = o1;
    const uint4 hv = *reinterpret_cast<const uint4*>(Ph + (size_t)col * 1024 + 512 + c8 * 8);
    const unsigned int w4[4] = {hv.x, hv.y, hv.z, hv.w};
#pragma unroll
    for (int p = 0; p < 4; ++p) {
      t[2 * p] += en[2 * p] * lof(w4[p]);
      t[2 * p + 1] += en[2 * p + 1] * hif(w4[p]);
    }
  }
#pragma unroll
  for (int j = 0; j < 8; ++j) red[sub][c8 * 8 + j] = t[j];
  __syncthreads();
  {
    const int c = threadIdx.x;
    float tt = 0.f;
#pragma unroll
    for (int u2 = 0; u2 < 8; ++u2) tt += red[u2][c];
    atomicAdd(T + c, tt);
  }
}

__global__ __launch_bounds__(256) void hout_k(
    const unsigned short* __restrict__ Ph, const float* __restrict__ T,
    float* __restrict__ outH, int nChunks) {
  const int g = blockIdx.x * 256 + threadIdx.x;
  if (g >= nChunks) return;
  const int i = g >> 5, c8 = g & 31;
  const uint4 hu = *reinterpret_cast<const uint4*>(Ph + (size_t)i * 1024 + 768 + c8 * 8);
  const float4 t0 = *reinterpret_cast<const float4*>(T + c8 * 8);
  const float4 t1 = *reinterpret_cast<const float4*>(T + c8 * 8 + 4);
  float4 o0, o1;
  o0.x = fmaxf(lof(hu.x) + t0.x, 0.f);
  o0.y = fmaxf(hif(hu.x) + t0.y, 0.f);
  o0.z = fmaxf(lof(hu.y) + t0.z, 0.f);
  o0.w = fmaxf(hif(hu.y) + t0.w, 0.f);
  o1.x = fmaxf(lof(hu.z) + t1.x, 0.f);
  o1.y = fmaxf(hif(hu.z) + t1.y, 0.f);
  o1.z = fmaxf(lof(hu.w) + t1.z, 0.f);
  o1.w = fmaxf(hif(hu.w) + t1.w, 0.f);
  float4* q = reinterpret_cast<float4*>(outH + (size_t)i * 256 + c8 * 8);
  q[0] = o0; q[1] = o1;
}

__global__ void pack_bias(const float* a, const float* b, const float* v, const float* u,
                          const float* cc, const float* dd,
                          float* biasH, float* biasE) {
  const int t = threadIdx.x;
  biasH[t] = a[t]; biasH[256 + t] = b[t]; biasH[512 + t] = v[t]; biasH[768 + t] = u[t];
  biasE[t] = cc[t]; biasE[256 + t] = dd[t];
}

// mode=1 iff edge_index is int64 on device (all high dwords of small values are 0)
__global__ void detect_idx(const int* __restrict__ ei, int* __restrict__ mode) {
  if (threadIdx.x == 0 && blockIdx.x == 0) {
    int m = 0;
#pragma unroll
    for (int i = 1; i < 64; i += 2) m |= ei[i];
    *mode = (m == 0) ? 1 : 0;
  }
}

extern "C" void kernel_launch(void* const* d_in, const int* in_sizes, int n_in,
                              void* d_out, int out_size, void* d_ws, size_t ws_size,
                              hipStream_t stream) {
  const float* h     = (const float*)d_in[0];
  const int*   ei    = (const int*)d_in[1];
  const float* e     = (const float*)d_in[2];
  const float* Aw    = (const float*)d_in[3];
  const float* Ab    = (const float*)d_in[4];
  const float* Bw    = (const float*)d_in[5];
  const float* Bb    = (const float*)d_in[6];
  const float* Cw    = (const float*)d_in[7];
  const float* Cb    = (const float*)d_in[8];
  const float* Dw    = (const float*)d_in[9];
  const float* Db    = (const float*)d_in[10];
  const float* gamma = (const float*)d_in[11];
  const float* beta  = (const float*)d_in[12];
  const float* Uw    = (const float*)d_in[13];
  const float* Ub    = (const float*)d_in[14];
  const float* Vw    = (const float*)d_in[15];
  const float* Vb    = (const float*)d_in[16];
  const int N = in_sizes[0] / 256;  // 131072

  char* ws = (char*)d_ws;
  unsigned short* WtH = (unsigned short*)(ws + 0x0);       // 512KB
  unsigned short* WtE = (unsigned short*)(ws + 0x80000);   // 256KB
  float* biasH  = (float*)(ws + 0xC0000);
  float* biasE  = (float*)(ws + 0xC1000);
  float* sums   = (float*)(ws + 0xC2000);
  float* sumsq  = (float*)(ws + 0xC2400);
  float* colsum = (float*)(ws + 0xC2800);
  float* Tacc   = (float*)(ws + 0xC2C00);
  float* scale  = (float*)(ws + 0xC3000);
  float* shift  = (float*)(ws + 0xC3400);
  float* inv    = (float*)(ws + 0xC3800);
  int*   mode   = (int*)(ws + 0xC3C00);
  // Region reuse across pipeline phases:
  unsigned short* R1 = (unsigned short*)(ws + 0x100000);    // 64MB : h_t, then e_out
  unsigned short* R3 = (unsigned short*)(ws + 0x4100000);   // 256MB: e_t (front), then P_h
  char*           R4 = ws + 0x14100000;                     // 128MB: P_e, then acc
  unsigned short* e_t  = R3;
  unsigned short* P_e  = (unsigned short*)R4;
  unsigned short* h_t  = R1;
  unsigned short* P_h  = R3;
  unsigned short* eout = R1;
  float*          acc  = (float*)R4;

  float* outH = (float*)d_out;
  float* outE = outH + (size_t)N * 256;

  hipMemsetAsync(ws + 0xC2000, 0, 4096, stream);                    // sums,sumsq,colsum,T
  detect_idx<<<1, 64, 0, stream>>>(ei, mode);
  pack_bias<<<1, 256, 0, stream>>>(Ab, Bb, Vb, Ub, Cb, Db, biasH, biasE);
  // weights -> tiled bf16 ([A|B|V|U] and [C|D])
  prep_tiled<<<32, 256, 0, stream>>>(Aw, WtH + 0 * 65536, 8192);
  prep_tiled<<<32, 256, 0, stream>>>(Bw, WtH + 1 * 65536, 8192);
  prep_tiled<<<32, 256, 0, stream>>>(Vw, WtH + 2 * 65536, 8192);
  prep_tiled<<<32, 256, 0, stream>>>(Uw, WtH + 3 * 65536, 8192);
  prep_tiled<<<32, 256, 0, stream>>>(Cw, WtE + 0 * 65536, 8192);
  prep_tiled<<<32, 256, 0, stream>>>(Dw, WtE + 1 * 65536, 8192);

  const int nChunks = N * 32;
  prep_tiled<<<nChunks / 256, 256, 0, stream>>>(e, e_t, nChunks);
  gemm_bt<<<(N / 128) * 4, 256, 0, stream>>>(e_t, WtE, biasE, P_e, 512, 4);
  prep_tiled<<<nChunks / 256, 256, 0, stream>>>(h, h_t, nChunks);
  gemm_bt<<<(N / 128) * 8, 256, 0, stream>>>(h_t, WtH, biasH, P_h, 1024, 8);  // overwrites e_t (dead)

  edge_sum<<<N / 64, 256, 0, stream>>>(P_h, P_e, ei, mode, eout, sums, sumsq, N);  // overwrites h_t (dead)
  bn_finalize<<<1, 256, 0, stream>>>(sums, sumsq, gamma, beta, scale, shift, 1.0f / (float)N);
  hipMemcpyAsync(acc, e, (size_t)N * 256 * 4, hipMemcpyDeviceToDevice, stream);    // overwrites P_e (dead)
  scatter_relu<<<N / 64, 256, 0, stream>>>(eout, ei, mode, scale, shift, acc, N);
  sigmoid_colsum<<<N / 64, 256, 0, stream>>>(acc, colsum);
  inv_finalize<<<1, 256, 0, stream>>>(colsum, inv);
  enew_T<<<N / 64, 256, 0, stream>>>(acc, inv, ei, mode, P_h, outE, Tacc, N);
  hout_k<<<nChunks / 256, 256, 0, stream>>>(P_h, Tacc, outH, nChunks);
}

// Round 2
// 658.551 us; speedup vs baseline: 2.3686x; 2.3686x over previous
//
#include <hip/hip_runtime.h>
#include <hip/hip_bf16.h>

// ---------------------------------------------------------------------------
// GatedNetwork: N = 131072 nodes == edges, C = 256 channels.
// Pipeline:
//   P_h = h @ [A|B|V|U]^T + bias   (bf16 MFMA GEMM, tiled-layout inputs)
//   P_e = e @ [C|D]^T + bias
//   e_out[k] = HA[row]+HB[col]+EC[col]+ED[row]   (+ batch stats)
//   counting-sort edges by row -> segmented gather:
//     acc[i] = sigmoid(e[i] + sum BNReLU(eout[k])) (+ colsum)
//   enew = acc/colsum; T[c] = sum_k enew[k][c]*HV[col[k]][c]
//   h_out = relu(HU + T)
// ---------------------------------------------------------------------------

typedef __attribute__((ext_vector_type(8))) short bf16x8;
typedef __attribute__((ext_vector_type(4))) float f32x4;

__device__ __forceinline__ float b2f(unsigned int lo16) {
  union { unsigned int u; float f; } c; c.u = lo16 << 16; return c.f;
}
__device__ __forceinline__ float lof(unsigned int u) { return b2f(u & 0xffffu); }
__device__ __forceinline__ float hif(unsigned int u) { return b2f(u >> 16); }
__device__ __forceinline__ unsigned int f2b(float f) {  // RNE f32->bf16
  union { float f; unsigned int u; } c; c.f = f;
  unsigned int u = c.u;
  u += 0x7fffu + ((u >> 16) & 1u);
  return u >> 16;
}

// --- prep: f32 row-major [M][256] -> bf16 tiled [M/16][32][16][8] ----------
__global__ __launch_bounds__(256) void prep_tiled(const float* __restrict__ src,
                                                  unsigned short* __restrict__ dst,
                                                  int nChunks) {
  int g = blockIdx.x * 256 + threadIdx.x;
  if (g >= nChunks) return;
  int mtile = g >> 9;
  int rem = g & 511;
  int r = rem >> 5, k8 = rem & 31;
  const float4* s = reinterpret_cast<const float4*>(src + (((size_t)mtile * 16 + r) << 8) + k8 * 8);
  float4 v0 = s[0], v1 = s[1];
  uint4 o;
  o.x = f2b(v0.x) | (f2b(v0.y) << 16);
  o.y = f2b(v0.z) | (f2b(v0.w) << 16);
  o.z = f2b(v1.x) | (f2b(v1.y) << 16);
  o.w = f2b(v1.z) | (f2b(v1.w) << 16);
  *reinterpret_cast<uint4*>(dst + ((size_t)mtile * 512 + k8 * 16 + r) * 8) = o;
}

// --- GEMM: C[m][o] = sum_k A[m][k]*B[o][k] + bias[o], bf16 in, bf16 out ----
__global__ __launch_bounds__(256) void gemm_bt(const unsigned short* __restrict__ At,
                                               const unsigned short* __restrict__ Bt,
                                               const float* __restrict__ bias,
                                               unsigned short* __restrict__ Cmat,
                                               int O, int nColBlk) {
  __shared__ char lds[16384];
  const int bid = blockIdx.x;
  const int colBlk = bid % nColBlk;
  const int rowBlk = bid / nColBlk;
  const int tid = threadIdx.x;
  const int w = tid >> 6, lane = tid & 63;
  const int wm = w >> 1, wn = w & 1;

  const char* Abase = (const char*)At + (size_t)(rowBlk * 8 + w * 2) * 8192 + lane * 16;
  const char* Bbase = (const char*)Bt + (size_t)(colBlk * 8 + w * 2) * 8192 + lane * 16;
  char* ldsA0 = lds + (w * 2) * 1024;
  char* ldsA1 = lds + (w * 2 + 1) * 1024;
  char* ldsB0 = lds + 8192 + (w * 2) * 1024;
  char* ldsB1 = lds + 8192 + (w * 2 + 1) * 1024;

  f32x4 acc[4][4] = {};

  for (int kt = 0; kt < 8; ++kt) {
    const size_t ko = (size_t)kt * 1024;
    __builtin_amdgcn_global_load_lds((const __attribute__((address_space(1))) void*)(Abase + ko),
                                     (__attribute__((address_space(3))) void*)ldsA0, 16, 0, 0);
    __builtin_amdgcn_global_load_lds((const __attribute__((address_space(1))) void*)(Abase + 8192 + ko),
                                     (__attribute__((address_space(3))) void*)ldsA1, 16, 0, 0);
    __builtin_amdgcn_global_load_lds((const __attribute__((address_space(1))) void*)(Bbase + ko),
                                     (__attribute__((address_space(3))) void*)ldsB0, 16, 0, 0);
    __builtin_amdgcn_global_load_lds((const __attribute__((address_space(1))) void*)(Bbase + 8192 + ko),
                                     (__attribute__((address_space(3))) void*)ldsB1, 16, 0, 0);
    __syncthreads();
    bf16x8 a[4], b[4];
#pragma unroll
    for (int mi = 0; mi < 4; ++mi)
      a[mi] = *reinterpret_cast<const bf16x8*>(lds + (wm * 4 + mi) * 1024 + lane * 16);
#pragma unroll
    for (int ni = 0; ni < 4; ++ni)
      b[ni] = *reinterpret_cast<const bf16x8*>(lds + 8192 + (wn * 4 + ni) * 1024 + lane * 16);
#pragma unroll
    for (int mi = 0; mi < 4; ++mi)
#pragma unroll
      for (int ni = 0; ni < 4; ++ni)
        acc[mi][ni] = __builtin_amdgcn_mfma_f32_16x16x32_bf16(a[mi], b[ni], acc[mi][ni], 0, 0, 0);
    __syncthreads();
  }

  const int rb = rowBlk * 128 + wm * 64 + ((lane >> 4) << 2);
  const int cb = colBlk * 128 + wn * 64 + (lane & 15);
#pragma unroll
  for (int mi = 0; mi < 4; ++mi) {
#pragma unroll
    for (int ni = 0; ni < 4; ++ni) {
      const int coln = cb + ni * 16;
      const float bz = bias[coln];
      const size_t base = (size_t)(rb + mi * 16) * O + coln;
#pragma unroll
      for (int r = 0; r < 4; ++r)
        Cmat[base + (size_t)r * O] = (unsigned short)f2b(acc[mi][ni][r] + bz);
    }
  }
}

// --- edge_sum: e_out[k] = HA[row]+HB[col]+EC[col]+ED[row]; accumulate stats -
__global__ __launch_bounds__(256) void edge_sum(
    const unsigned short* __restrict__ Ph, const unsigned short* __restrict__ Pe,
    const int* __restrict__ ei, const int* __restrict__ modep,
    unsigned short* __restrict__ eout,
    float* __restrict__ sums, float* __restrict__ sumsq, int Nn) {
  __shared__ float red[8][256];
  const int c8 = threadIdx.x & 31;
  const int sub = threadIdx.x >> 5;
  const int mode = *modep;
  float s[8], q[8];
#pragma unroll
  for (int j = 0; j < 8; ++j) { s[j] = 0.f; q[j] = 0.f; }

#pragma unroll 1
  for (int it = 0; it < 8; ++it) {
    const int k = blockIdx.x * 64 + it * 8 + sub;
    int row, col;
    if (mode) { row = ei[2 * k]; col = ei[2 * (Nn + k)]; }
    else      { row = ei[k];     col = ei[Nn + k]; }
    const uint4 ha = *reinterpret_cast<const uint4*>(Ph + (size_t)row * 1024 + c8 * 8);
    const uint4 hb = *reinterpret_cast<const uint4*>(Ph + (size_t)col * 1024 + 256 + c8 * 8);
    const uint4 ec = *reinterpret_cast<const uint4*>(Pe + (size_t)col * 512 + c8 * 8);
    const uint4 ed = *reinterpret_cast<const uint4*>(Pe + (size_t)row * 512 + 256 + c8 * 8);
    const unsigned int aw[4] = {ha.x, ha.y, ha.z, ha.w};
    const unsigned int bw[4] = {hb.x, hb.y, hb.z, hb.w};
    const unsigned int cw[4] = {ec.x, ec.y, ec.z, ec.w};
    const unsigned int dw[4] = {ed.x, ed.y, ed.z, ed.w};
    unsigned int ow[4];
#pragma unroll
    for (int p = 0; p < 4; ++p) {
      float v0 = lof(aw[p]) + lof(bw[p]) + lof(cw[p]) + lof(dw[p]);
      float v1 = hif(aw[p]) + hif(bw[p]) + hif(cw[p]) + hif(dw[p]);
      s[2 * p] += v0;     q[2 * p] += v0 * v0;
      s[2 * p + 1] += v1; q[2 * p + 1] += v1 * v1;
      ow[p] = f2b(v0) | (f2b(v1) << 16);
    }
    uint4 o; o.x = ow[0]; o.y = ow[1]; o.z = ow[2]; o.w = ow[3];
    *reinterpret_cast<uint4*>(eout + (size_t)k * 256 + c8 * 8) = o;
  }
#pragma unroll
  for (int j = 0; j < 8; ++j) red[sub][c8 * 8 + j] = s[j];
  __syncthreads();
  {
    const int c = threadIdx.x;
    float t = 0.f;
#pragma unroll
    for (int u2 = 0; u2 < 8; ++u2) t += red[u2][c];
    atomicAdd(sums + c, t);
  }
  __syncthreads();
#pragma unroll
  for (int j = 0; j < 8; ++j) red[sub][c8 * 8 + j] = q[j];
  __syncthreads();
  {
    const int c = threadIdx.x;
    float t = 0.f;
#pragma unroll
    for (int u2 = 0; u2 < 8; ++u2) t += red[u2][c];
    atomicAdd(sumsq + c, t);
  }
}

__global__ void bn_finalize(const float* __restrict__ sums, const float* __restrict__ sumsq,
                            const float* __restrict__ gamma, const float* __restrict__ beta,
                            float* __restrict__ scale, float* __restrict__ shift, float invE) {
  const int c = threadIdx.x;
  const float mu = sums[c] * invE;
  const float var = fmaxf(sumsq[c] * invE - mu * mu, 0.f);
  const float sc = gamma[c] * rsqrtf(var + 1e-5f);
  scale[c] = sc;
  shift[c] = beta[c] - mu * sc;
}

// --- counting sort of edges by row -----------------------------------------
__global__ __launch_bounds__(256) void hist_rows(const int* __restrict__ ei,
                                                 const int* __restrict__ modep,
                                                 int* __restrict__ cnt, int Nn) {
  const int k = blockIdx.x * 256 + threadIdx.x;
  if (k >= Nn) return;
  const int row = (*modep) ? ei[2 * k] : ei[k];
  atomicAdd(&cnt[row], 1);
}

__global__ __launch_bounds__(256) void scan1(const int* __restrict__ cnt,
                                             int* __restrict__ bsum) {
  __shared__ int red[256];
  const int t = threadIdx.x;
  red[t] = cnt[blockIdx.x * 256 + t];
  __syncthreads();
#pragma unroll
  for (int s = 128; s > 0; s >>= 1) {
    if (t < s) red[t] += red[t + s];
    __syncthreads();
  }
  if (t == 0) bsum[blockIdx.x] = red[0];
}

__global__ __launch_bounds__(512) void scan2(int* __restrict__ bsum, int nb) {
  __shared__ int tmp[512];
  const int t = threadIdx.x;
  const int own = (t < nb) ? bsum[t] : 0;
  tmp[t] = own;
  __syncthreads();
  for (int off = 1; off < 512; off <<= 1) {
    int v = (t >= off) ? tmp[t - off] : 0;
    __syncthreads();
    tmp[t] += v;
    __syncthreads();
  }
  if (t < nb) bsum[t] = tmp[t] - own;  // exclusive
}

__global__ __launch_bounds__(256) void scan3(const int* __restrict__ cnt,
                                             const int* __restrict__ bsum,
                                             int* __restrict__ base, int Nn) {
  __shared__ int tmp[256];
  const int t = threadIdx.x;
  const int gid = blockIdx.x * 256 + t;
  const int own = cnt[gid];
  tmp[t] = own;
  __syncthreads();
  for (int off = 1; off < 256; off <<= 1) {
    int v = (t >= off) ? tmp[t - off] : 0;
    __syncthreads();
    tmp[t] += v;
    __syncthreads();
  }
  base[gid] = tmp[t] - own + bsum[blockIdx.x];
  if (gid == 0) base[Nn] = Nn;  // E == N
}

__global__ __launch_bounds__(256) void scatter_eids(const int* __restrict__ ei,
                                                    const int* __restrict__ modep,
                                                    const int* __restrict__ base,
                                                    int* __restrict__ cnt,
                                                    int* __restrict__ sorted, int Nn) {
  const int k = blockIdx.x * 256 + threadIdx.x;
  if (k >= Nn) return;
  const int row = (*modep) ? ei[2 * k] : ei[k];
  const int pos = base[row] + atomicAdd(&cnt[row], -1) - 1;
  sorted[pos] = k;
}

// --- fused: acc[i] = sigmoid(e[i] + sum_k BNReLU(eout[k])); colsum += acc ---
__global__ __launch_bounds__(256) void gather_sig_colsum(
    const float* __restrict__ e, const unsigned short* __restrict__ eout,
    const int* __restrict__ base, const int* __restrict__ sorted,
    const float* __restrict__ scale, const float* __restrict__ shift,
    float* __restrict__ acc, float* __restrict__ colsum) {
  __shared__ float red[4][256];
  const int lane = threadIdx.x & 63, w = threadIdx.x >> 6;
  const float4 sc = *reinterpret_cast<const float4*>(scale + lane * 4);
  const float4 sh = *reinterpret_cast<const float4*>(shift + lane * 4);
  float s0 = 0.f, s1 = 0.f, s2 = 0.f, s3 = 0.f;
  const int n0 = blockIdx.x * 64 + w * 16;
#pragma unroll 1
  for (int it = 0; it < 16; ++it) {
    const int i = n0 + it;
    float4 v = *reinterpret_cast<const float4*>(e + (size_t)i * 256 + lane * 4);
    const int p0 = base[i], p1 = base[i + 1];
#pragma unroll 1
    for (int p = p0; p < p1; ++p) {
      const int eid = sorted[p];
      const uint2 wv = *reinterpret_cast<const uint2*>(eout + (size_t)eid * 256 + lane * 4);
      v.x += fmaxf(fmaf(sc.x, lof(wv.x), sh.x), 0.f);
      v.y += fmaxf(fmaf(sc.y, hif(wv.x), sh.y), 0.f);
      v.z += fmaxf(fmaf(sc.z, lof(wv.y), sh.z), 0.f);
      v.w += fmaxf(fmaf(sc.w, hif(wv.y), sh.w), 0.f);
    }
    v.x = 1.f / (1.f + __expf(-v.x));
    v.y = 1.f / (1.f + __expf(-v.y));
    v.z = 1.f / (1.f + __expf(-v.z));
    v.w = 1.f / (1.f + __expf(-v.w));
    *reinterpret_cast<float4*>(acc + (size_t)i * 256 + lane * 4) = v;
    s0 += v.x; s1 += v.y; s2 += v.z; s3 += v.w;
  }
  red[w][lane * 4 + 0] = s0;
  red[w][lane * 4 + 1] = s1;
  red[w][lane * 4 + 2] = s2;
  red[w][lane * 4 + 3] = s3;
  __syncthreads();
  const int c = threadIdx.x;
  atomicAdd(colsum + c, red[0][c] + red[1][c] + red[2][c] + red[3][c]);
}

__global__ void inv_finalize(const float* __restrict__ colsum, float* __restrict__ inv) {
  const int c = threadIdx.x;
  inv[c] = 1.0f / (colsum[c] + 1e-5f);
}

__global__ __launch_bounds__(256) void enew_T(
    const float* __restrict__ acc, const float* __restrict__ inv,
    const int* __restrict__ ei, const int* __restrict__ modep,
    const unsigned short* __restrict__ Ph,
    float* __restrict__ outE, float* __restrict__ T, int Nn) {
  __shared__ float red[8][256];
  const int c8 = threadIdx.x & 31, sub = threadIdx.x >> 5;
  const int mode = *modep;
  float iv[8];
#pragma unroll
  for (int j = 0; j < 8; ++j) iv[j] = inv[c8 * 8 + j];
  float t[8];
#pragma unroll
  for (int j = 0; j < 8; ++j) t[j] = 0.f;
#pragma unroll 1
  for (int it = 0; it < 8; ++it) {
    const int k = blockIdx.x * 64 + it * 8 + sub;
    const int col = mode ? ei[2 * (Nn + k)] : ei[Nn + k];
    const float4* p0 = reinterpret_cast<const float4*>(acc + (size_t)k * 256 + c8 * 8);
    const float4 a = p0[0], b = p0[1];
    float en[8] = {a.x * iv[0], a.y * iv[1], a.z * iv[2], a.w * iv[3],
                   b.x * iv[4], b.y * iv[5], b.z * iv[6], b.w * iv[7]};
    float4 o0, o1;
    o0.x = en[0]; o0.y = en[1]; o0.z = en[2]; o0.w = en[3];
    o1.x = en[4]; o1.y = en[5]; o1.z = en[6]; o1.w = en[7];
    float4* q0 = reinterpret_cast<float4*>(outE + (size_t)k * 256 + c8 * 8);
    q0[0] = o0; q0[1] = o1;
    const uint4 hv = *reinterpret_cast<const uint4*>(Ph + (size_t)col * 1024 + 512 + c8 * 8);
    const unsigned int w4[4] = {hv.x, hv.y, hv.z, hv.w};
#pragma unroll
    for (int p = 0; p < 4; ++p) {
      t[2 * p] += en[2 * p] * lof(w4[p]);
      t[2 * p + 1] += en[2 * p + 1] * hif(w4[p]);
    }
  }
#pragma unroll
  for (int j = 0; j < 8; ++j) red[sub][c8 * 8 + j] = t[j];
  __syncthreads();
  {
    const int c = threadIdx.x;
    float tt = 0.f;
#pragma unroll
    for (int u2 = 0; u2 < 8; ++u2) tt += red[u2][c];
    atomicAdd(T + c, tt);
  }
}

__global__ __launch_bounds__(256) void hout_k(
    const unsigned short* __restrict__ Ph, const float* __restrict__ T,
    float* __restrict__ outH, int nChunks) {
  const int g = blockIdx.x * 256 + threadIdx.x;
  if (g >= nChunks) return;
  const int i = g >> 5, c8 = g & 31;
  const uint4 hu = *reinterpret_cast<const uint4*>(Ph + (size_t)i * 1024 + 768 + c8 * 8);
  const float4 t0 = *reinterpret_cast<const float4*>(T + c8 * 8);
  const float4 t1 = *reinterpret_cast<const float4*>(T + c8 * 8 + 4);
  float4 o0, o1;
  o0.x = fmaxf(lof(hu.x) + t0.x, 0.f);
  o0.y = fmaxf(hif(hu.x) + t0.y, 0.f);
  o0.z = fmaxf(lof(hu.y) + t0.z, 0.f);
  o0.w = fmaxf(hif(hu.y) + t0.w, 0.f);
  o1.x = fmaxf(lof(hu.z) + t1.x, 0.f);
  o1.y = fmaxf(hif(hu.z) + t1.y, 0.f);
  o1.z = fmaxf(lof(hu.w) + t1.z, 0.f);
  o1.w = fmaxf(hif(hu.w) + t1.w, 0.f);
  float4* q = reinterpret_cast<float4*>(outH + (size_t)i * 256 + c8 * 8);
  q[0] = o0; q[1] = o1;
}

__global__ void pack_bias(const float* a, const float* b, const float* v, const float* u,
                          const float* cc, const float* dd,
                          float* biasH, float* biasE) {
  const int t = threadIdx.x;
  biasH[t] = a[t]; biasH[256 + t] = b[t]; biasH[512 + t] = v[t]; biasH[768 + t] = u[t];
  biasE[t] = cc[t]; biasE[256 + t] = dd[t];
}

// mode=1 iff edge_index is int64 on device (all high dwords of small values are 0)
__global__ void detect_idx(const int* __restrict__ ei, int* __restrict__ mode) {
  if (threadIdx.x == 0 && blockIdx.x == 0) {
    int m = 0;
#pragma unroll
    for (int i = 1; i < 64; i += 2) m |= ei[i];
    *mode = (m == 0) ? 1 : 0;
  }
}

extern "C" void kernel_launch(void* const* d_in, const int* in_sizes, int n_in,
                              void* d_out, int out_size, void* d_ws, size_t ws_size,
                              hipStream_t stream) {
  const float* h     = (const float*)d_in[0];
  const int*   ei    = (const int*)d_in[1];
  const float* e     = (const float*)d_in[2];
  const float* Aw    = (const float*)d_in[3];
  const float* Ab    = (const float*)d_in[4];
  const float* Bw    = (const float*)d_in[5];
  const float* Bb    = (const float*)d_in[6];
  const float* Cw    = (const float*)d_in[7];
  const float* Cb    = (const float*)d_in[8];
  const float* Dw    = (const float*)d_in[9];
  const float* Db    = (const float*)d_in[10];
  const float* gamma = (const float*)d_in[11];
  const float* beta  = (const float*)d_in[12];
  const float* Uw    = (const float*)d_in[13];
  const float* Ub    = (const float*)d_in[14];
  const float* Vw    = (const float*)d_in[15];
  const float* Vb    = (const float*)d_in[16];
  const int N = in_sizes[0] / 256;  // 131072

  char* ws = (char*)d_ws;
  unsigned short* WtH = (unsigned short*)(ws + 0x0);       // 512KB
  unsigned short* WtE = (unsigned short*)(ws + 0x80000);   // 256KB
  float* biasH  = (float*)(ws + 0xC0000);
  float* biasE  = (float*)(ws + 0xC1000);
  float* sums   = (float*)(ws + 0xC2000);
  float* sumsq  = (float*)(ws + 0xC2400);
  float* colsum = (float*)(ws + 0xC2800);
  float* Tacc   = (float*)(ws + 0xC2C00);
  float* scale  = (float*)(ws + 0xC3000);
  float* shift  = (float*)(ws + 0xC3400);
  float* inv    = (float*)(ws + 0xC3800);
  int*   mode   = (int*)(ws + 0xC3C00);
  // Region reuse across pipeline phases:
  unsigned short* R1 = (unsigned short*)(ws + 0x100000);    // 64MB : h_t, then e_out
  unsigned short* R3 = (unsigned short*)(ws + 0x4100000);   // 256MB: e_t (front), then P_h
  char*           R4 = ws + 0x14100000;                     // 128MB: P_e, then acc
  // counting-sort scratch (beyond R4: +1.6MB)
  int* cnt    = (int*)(ws + 0x1C100000);                    // 512KB
  int* baseA  = (int*)(ws + 0x1C180000);                    // 512KB+4
  int* sorted = (int*)(ws + 0x1C210000);                    // 512KB
  int* bsum   = (int*)(ws + 0x1C290000);                    // 2KB

  unsigned short* e_t  = R3;
  unsigned short* P_e  = (unsigned short*)R4;
  unsigned short* h_t  = R1;
  unsigned short* P_h  = R3;
  unsigned short* eout = R1;
  float*          acc  = (float*)R4;

  float* outH = (float*)d_out;
  float* outE = outH + (size_t)N * 256;

  hipMemsetAsync(ws + 0xC2000, 0, 4096, stream);                    // sums,sumsq,colsum,T
  hipMemsetAsync(cnt, 0, (size_t)N * 4, stream);
  detect_idx<<<1, 64, 0, stream>>>(ei, mode);
  pack_bias<<<1, 256, 0, stream>>>(Ab, Bb, Vb, Ub, Cb, Db, biasH, biasE);
  // weights -> tiled bf16 ([A|B|V|U] and [C|D])
  prep_tiled<<<32, 256, 0, stream>>>(Aw, WtH + 0 * 65536, 8192);
  prep_tiled<<<32, 256, 0, stream>>>(Bw, WtH + 1 * 65536, 8192);
  prep_tiled<<<32, 256, 0, stream>>>(Vw, WtH + 2 * 65536, 8192);
  prep_tiled<<<32, 256, 0, stream>>>(Uw, WtH + 3 * 65536, 8192);
  prep_tiled<<<32, 256, 0, stream>>>(Cw, WtE + 0 * 65536, 8192);
  prep_tiled<<<32, 256, 0, stream>>>(Dw, WtE + 1 * 65536, 8192);

  // counting sort of edges by row (only needs ei)
  hist_rows<<<N / 256, 256, 0, stream>>>(ei, mode, cnt, N);
  scan1<<<N / 256 / 256 ? 512 : 512, 256, 0, stream>>>(cnt, bsum);  // 512 blocks
  scan2<<<1, 512, 0, stream>>>(bsum, N / 256);
  scan3<<<N / 256, 256, 0, stream>>>(cnt, bsum, baseA, N);
  scatter_eids<<<N / 256, 256, 0, stream>>>(ei, mode, baseA, cnt, sorted, N);

  const int nChunks = N * 32;
  prep_tiled<<<nChunks / 256, 256, 0, stream>>>(e, e_t, nChunks);
  gemm_bt<<<(N / 128) * 4, 256, 0, stream>>>(e_t, WtE, biasE, P_e, 512, 4);
  prep_tiled<<<nChunks / 256, 256, 0, stream>>>(h, h_t, nChunks);
  gemm_bt<<<(N / 128) * 8, 256, 0, stream>>>(h_t, WtH, biasH, P_h, 1024, 8);  // overwrites e_t (dead)

  edge_sum<<<N / 64, 256, 0, stream>>>(P_h, P_e, ei, mode, eout, sums, sumsq, N);  // overwrites h_t (dead)
  bn_finalize<<<1, 256, 0, stream>>>(sums, sumsq, gamma, beta, scale, shift, 1.0f / (float)N);
  gather_sig_colsum<<<N / 64, 256, 0, stream>>>(e, eout, baseA, sorted, scale, shift, acc, colsum);  // overwrites P_e (dead)
  inv_finalize<<<1, 256, 0, stream>>>(colsum, inv);
  enew_T<<<N / 64, 256, 0, stream>>>(acc, inv, ei, mode, P_h, outE, Tacc, N);
  hout_k<<<nChunks / 256, 256, 0, stream>>>(P_h, Tacc, outH, nChunks);
}

// Round 3
// 639.419 us; speedup vs baseline: 2.4394x; 1.0299x over previous
//
#include <hip/hip_runtime.h>
#include <hip/hip_bf16.h>

// ---------------------------------------------------------------------------
// GatedNetwork: N = 131072 nodes == edges, C = 256 channels.
// Algebraic factorization: e_out[k] = PR[row[k]] + PC[col[k]] where
//   PR = h@A^T + e@D^T + (Ab+Db),  PC = h@B^T + e@C^T + (Bb+Cb)
// Pipeline:
//   GEMM1 (two-source K=512): PRPC[i] = [PR|PC]  (bf16, 128 MiB)
//   GEMM2 (K=256):            VU[i]   = [HV|HU]
//   counting-sort edges by row (rows_sorted/cols_sorted)
//   edge_stats: BN batch stats over PR[row]+PC[col]  (PR streamed, PC gathered)
//   gather: acc[i] = sigmoid(e[i] + sum_seg relu(sc*(PR[i]+PC[col])+sh)) + colsum
//   enew_T: outE = acc*inv; T += acc*inv * HV[col]
//   hout:   outH = relu(HU + T)
// ---------------------------------------------------------------------------

typedef __attribute__((ext_vector_type(8))) short bf16x8;
typedef __attribute__((ext_vector_type(4))) float f32x4;

__device__ __forceinline__ float b2f(unsigned int lo16) {
  union { unsigned int u; float f; } c; c.u = lo16 << 16; return c.f;
}
__device__ __forceinline__ float lof(unsigned int u) { return b2f(u & 0xffffu); }
__device__ __forceinline__ float hif(unsigned int u) { return b2f(u >> 16); }
__device__ __forceinline__ unsigned int f2b(float f) {  // RNE f32->bf16
  union { float f; unsigned int u; } c; c.f = f;
  unsigned int u = c.u;
  u += 0x7fffu + ((u >> 16) & 1u);
  return u >> 16;
}

// --- prep: f32 row-major [M][256] -> bf16 tiled [M/16][32][16][8] ----------
__global__ __launch_bounds__(256) void prep_tiled(const float* __restrict__ src,
                                                  unsigned short* __restrict__ dst,
                                                  int nChunks) {
  int g = blockIdx.x * 256 + threadIdx.x;
  if (g >= nChunks) return;
  int mtile = g >> 9;
  int rem = g & 511;
  int r = rem >> 5, k8 = rem & 31;
  const float4* s = reinterpret_cast<const float4*>(src + (((size_t)mtile * 16 + r) << 8) + k8 * 8);
  float4 v0 = s[0], v1 = s[1];
  uint4 o;
  o.x = f2b(v0.x) | (f2b(v0.y) << 16);
  o.y = f2b(v0.z) | (f2b(v0.w) << 16);
  o.z = f2b(v1.x) | (f2b(v1.y) << 16);
  o.w = f2b(v1.z) | (f2b(v1.w) << 16);
  *reinterpret_cast<uint4*>(dst + ((size_t)mtile * 512 + k8 * 16 + r) * 8) = o;
}

// --- GEMM (two K-sources): C[m][o] = sum_k Ah[m][k]Bh[o][k] (+ Ae*Be) + bias
// kt<8 reads (Ah,Bh), kt>=8 reads (Ae,Be). ktSteps=8 -> single-source K=256.
__global__ __launch_bounds__(256) void gemm_bt2(
    const unsigned short* __restrict__ Ah, const unsigned short* __restrict__ Ae,
    const unsigned short* __restrict__ Bh, const unsigned short* __restrict__ Be,
    const float* __restrict__ bias, unsigned short* __restrict__ Cmat,
    int O, int nColBlk, int ktSteps, int nBlk) {
  __shared__ char lds[16384];
  // bijective XCD swizzle (nBlk % 8 == 0): XCD gets contiguous work chunk so
  // the nColBlk blocks sharing an A-panel land in one L2.
  const int cpx = nBlk >> 3;
  const int hw = blockIdx.x;
  const int bid = (hw % 8) * cpx + hw / 8;
  const int colBlk = bid % nColBlk;
  const int rowBlk = bid / nColBlk;
  const int tid = threadIdx.x;
  const int w = tid >> 6, lane = tid & 63;
  const int wm = w >> 1, wn = w & 1;

  const size_t aTileOff = (size_t)(rowBlk * 8 + w * 2) * 8192 + lane * 16;
  const size_t bTileOff = (size_t)(colBlk * 8 + w * 2) * 8192 + lane * 16;
  char* ldsA0 = lds + (w * 2) * 1024;
  char* ldsA1 = lds + (w * 2 + 1) * 1024;
  char* ldsB0 = lds + 8192 + (w * 2) * 1024;
  char* ldsB1 = lds + 8192 + (w * 2 + 1) * 1024;

  f32x4 acc[4][4] = {};

  for (int kt = 0; kt < ktSteps; ++kt) {
    const char* Abase = (const char*)(kt < 8 ? Ah : Ae) + aTileOff + (size_t)(kt & 7) * 1024;
    const char* Bbase = (const char*)(kt < 8 ? Bh : Be) + bTileOff + (size_t)(kt & 7) * 1024;
    __builtin_amdgcn_global_load_lds((const __attribute__((address_space(1))) void*)Abase,
                                     (__attribute__((address_space(3))) void*)ldsA0, 16, 0, 0);
    __builtin_amdgcn_global_load_lds((const __attribute__((address_space(1))) void*)(Abase + 8192),
                                     (__attribute__((address_space(3))) void*)ldsA1, 16, 0, 0);
    __builtin_amdgcn_global_load_lds((const __attribute__((address_space(1))) void*)Bbase,
                                     (__attribute__((address_space(3))) void*)ldsB0, 16, 0, 0);
    __builtin_amdgcn_global_load_lds((const __attribute__((address_space(1))) void*)(Bbase + 8192),
                                     (__attribute__((address_space(3))) void*)ldsB1, 16, 0, 0);
    __syncthreads();  // drains vmcnt(0): LDS tiles ready
    bf16x8 a[4], b[4];
#pragma unroll
    for (int mi = 0; mi < 4; ++mi)
      a[mi] = *reinterpret_cast<const bf16x8*>(lds + (wm * 4 + mi) * 1024 + lane * 16);
#pragma unroll
    for (int ni = 0; ni < 4; ++ni)
      b[ni] = *reinterpret_cast<const bf16x8*>(lds + 8192 + (wn * 4 + ni) * 1024 + lane * 16);
#pragma unroll
    for (int mi = 0; mi < 4; ++mi)
#pragma unroll
      for (int ni = 0; ni < 4; ++ni)
        acc[mi][ni] = __builtin_amdgcn_mfma_f32_16x16x32_bf16(a[mi], b[ni], acc[mi][ni], 0, 0, 0);
    __syncthreads();  // compute done before next stage overwrites
  }

  const int rb = rowBlk * 128 + wm * 64 + ((lane >> 4) << 2);
  const int cb = colBlk * 128 + wn * 64 + (lane & 15);
#pragma unroll
  for (int mi = 0; mi < 4; ++mi) {
#pragma unroll
    for (int ni = 0; ni < 4; ++ni) {
      const int coln = cb + ni * 16;
      const float bz = bias[coln];
      const size_t base = (size_t)(rb + mi * 16) * O + coln;
#pragma unroll
      for (int r = 0; r < 4; ++r)
        Cmat[base + (size_t)r * O] = (unsigned short)f2b(acc[mi][ni][r] + bz);
    }
  }
}

// --- BN batch stats over e_out[p] = PR[rows_s[p]] + PC[cols_s[p]] ----------
// p iterates in row-sorted order: PR reads near-sequential, PC gathered.
__global__ __launch_bounds__(256) void edge_stats(
    const unsigned short* __restrict__ PRPC,
    const int* __restrict__ rows_s, const int* __restrict__ cols_s,
    float* __restrict__ sums, float* __restrict__ sumsq) {
  __shared__ float red[8][256];
  const int c8 = threadIdx.x & 31;
  const int sub = threadIdx.x >> 5;
  float s[8], q[8];
#pragma unroll
  for (int j = 0; j < 8; ++j) { s[j] = 0.f; q[j] = 0.f; }
#pragma unroll 1
  for (int it = 0; it < 8; ++it) {
    const int p = blockIdx.x * 64 + it * 8 + sub;
    const int r = rows_s[p], cj = cols_s[p];
    const uint4 pr = *reinterpret_cast<const uint4*>(PRPC + (size_t)r * 512 + c8 * 8);
    const uint4 pc = *reinterpret_cast<const uint4*>(PRPC + (size_t)cj * 512 + 256 + c8 * 8);
    const unsigned int rw[4] = {pr.x, pr.y, pr.z, pr.w};
    const unsigned int cw[4] = {pc.x, pc.y, pc.z, pc.w};
#pragma unroll
    for (int p4 = 0; p4 < 4; ++p4) {
      const float v0 = lof(rw[p4]) + lof(cw[p4]);
      const float v1 = hif(rw[p4]) + hif(cw[p4]);
      s[2 * p4] += v0;     q[2 * p4] += v0 * v0;
      s[2 * p4 + 1] += v1; q[2 * p4 + 1] += v1 * v1;
    }
  }
#pragma unroll
  for (int j = 0; j < 8; ++j) red[sub][c8 * 8 + j] = s[j];
  __syncthreads();
  {
    const int c = threadIdx.x;
    float t = 0.f;
#pragma unroll
    for (int u2 = 0; u2 < 8; ++u2) t += red[u2][c];
    atomicAdd(sums + c, t);
  }
  __syncthreads();
#pragma unroll
  for (int j = 0; j < 8; ++j) red[sub][c8 * 8 + j] = q[j];
  __syncthreads();
  {
    const int c = threadIdx.x;
    float t = 0.f;
#pragma unroll
    for (int u2 = 0; u2 < 8; ++u2) t += red[u2][c];
    atomicAdd(sumsq + c, t);
  }
}

__global__ void bn_finalize(const float* __restrict__ sums, const float* __restrict__ sumsq,
                            const float* __restrict__ gamma, const float* __restrict__ beta,
                            float* __restrict__ scale, float* __restrict__ shift, float invE) {
  const int c = threadIdx.x;
  const float mu = sums[c] * invE;
  const float var = fmaxf(sumsq[c] * invE - mu * mu, 0.f);
  const float sc = gamma[c] * rsqrtf(var + 1e-5f);
  scale[c] = sc;
  shift[c] = beta[c] - mu * sc;
}

// --- counting sort of edges by row -----------------------------------------
__global__ __launch_bounds__(256) void hist_rows(const int* __restrict__ ei,
                                                 const int* __restrict__ modep,
                                                 int* __restrict__ cnt, int Nn) {
  const int k = blockIdx.x * 256 + threadIdx.x;
  if (k >= Nn) return;
  const int row = (*modep) ? ei[2 * k] : ei[k];
  atomicAdd(&cnt[row], 1);
}

__global__ __launch_bounds__(256) void scan1(const int* __restrict__ cnt,
                                             int* __restrict__ bsum) {
  __shared__ int red[256];
  const int t = threadIdx.x;
  red[t] = cnt[blockIdx.x * 256 + t];
  __syncthreads();
#pragma unroll
  for (int s = 128; s > 0; s >>= 1) {
    if (t < s) red[t] += red[t + s];
    __syncthreads();
  }
  if (t == 0) bsum[blockIdx.x] = red[0];
}

__global__ __launch_bounds__(512) void scan2(int* __restrict__ bsum, int nb) {
  __shared__ int tmp[512];
  const int t = threadIdx.x;
  const int own = (t < nb) ? bsum[t] : 0;
  tmp[t] = own;
  __syncthreads();
  for (int off = 1; off < 512; off <<= 1) {
    int v = (t >= off) ? tmp[t - off] : 0;
    __syncthreads();
    tmp[t] += v;
    __syncthreads();
  }
  if (t < nb) bsum[t] = tmp[t] - own;  // exclusive
}

__global__ __launch_bounds__(256) void scan3(const int* __restrict__ cnt,
                                             const int* __restrict__ bsum,
                                             int* __restrict__ base, int Nn) {
  __shared__ int tmp[256];
  const int t = threadIdx.x;
  const int gid = blockIdx.x * 256 + t;
  const int own = cnt[gid];
  tmp[t] = own;
  __syncthreads();
  for (int off = 1; off < 256; off <<= 1) {
    int v = (t >= off) ? tmp[t - off] : 0;
    __syncthreads();
    tmp[t] += v;
    __syncthreads();
  }
  base[gid] = tmp[t] - own + bsum[blockIdx.x];
  if (gid == 0) base[Nn] = Nn;  // E == N
}

__global__ __launch_bounds__(256) void scatter_eids(const int* __restrict__ ei,
                                                    const int* __restrict__ modep,
                                                    const int* __restrict__ base,
                                                    int* __restrict__ cnt,
                                                    int* __restrict__ rows_s,
                                                    int* __restrict__ cols_s, int Nn) {
  const int k = blockIdx.x * 256 + threadIdx.x;
  if (k >= Nn) return;
  int row, col;
  if (*modep) { row = ei[2 * k]; col = ei[2 * (Nn + k)]; }
  else        { row = ei[k];     col = ei[Nn + k]; }
  const int pos = base[row] + atomicAdd(&cnt[row], -1) - 1;
  rows_s[pos] = row;
  cols_s[pos] = col;
}

// --- fused: acc[i] = sigmoid(e[i] + sum_seg relu(sc*(PR[i]+PC[col])+sh)) ----
__global__ __launch_bounds__(256) void gather_sig_colsum(
    const float* __restrict__ e, const unsigned short* __restrict__ PRPC,
    const int* __restrict__ base, const int* __restrict__ cols_s,
    const float* __restrict__ scale, const float* __restrict__ shift,
    float* __restrict__ acc, float* __restrict__ colsum) {
  __shared__ float red[4][256];
  const int lane = threadIdx.x & 63, w = threadIdx.x >> 6;
  const float4 sc = *reinterpret_cast<const float4*>(scale + lane * 4);
  const float4 sh = *reinterpret_cast<const float4*>(shift + lane * 4);
  float s0 = 0.f, s1 = 0.f, s2 = 0.f, s3 = 0.f;
  const int n0 = blockIdx.x * 64 + w * 16;
#pragma unroll 1
  for (int it = 0; it < 16; ++it) {
    const int i = n0 + it;
    float4 v = *reinterpret_cast<const float4*>(e + (size_t)i * 256 + lane * 4);
    const uint2 pr = *reinterpret_cast<const uint2*>(PRPC + (size_t)i * 512 + lane * 4);
    const float pr0 = lof(pr.x), pr1 = hif(pr.x), pr2 = lof(pr.y), pr3 = hif(pr.y);
    const int p0 = base[i], p1 = base[i + 1];
#pragma unroll 1
    for (int p = p0; p < p1; ++p) {
      const int cj = cols_s[p];
      const uint2 pc = *reinterpret_cast<const uint2*>(PRPC + (size_t)cj * 512 + 256 + lane * 4);
      v.x += fmaxf(fmaf(sc.x, pr0 + lof(pc.x), sh.x), 0.f);
      v.y += fmaxf(fmaf(sc.y, pr1 + hif(pc.x), sh.y), 0.f);
      v.z += fmaxf(fmaf(sc.z, pr2 + lof(pc.y), sh.z), 0.f);
      v.w += fmaxf(fmaf(sc.w, pr3 + hif(pc.y), sh.w), 0.f);
    }
    v.x = 1.f / (1.f + __expf(-v.x));
    v.y = 1.f / (1.f + __expf(-v.y));
    v.z = 1.f / (1.f + __expf(-v.z));
    v.w = 1.f / (1.f + __expf(-v.w));
    *reinterpret_cast<float4*>(acc + (size_t)i * 256 + lane * 4) = v;
    s0 += v.x; s1 += v.y; s2 += v.z; s3 += v.w;
  }
  red[w][lane * 4 + 0] = s0;
  red[w][lane * 4 + 1] = s1;
  red[w][lane * 4 + 2] = s2;
  red[w][lane * 4 + 3] = s3;
  __syncthreads();
  const int c = threadIdx.x;
  atomicAdd(colsum + c, red[0][c] + red[1][c] + red[2][c] + red[3][c]);
}

__global__ void inv_finalize(const float* __restrict__ colsum, float* __restrict__ inv) {
  const int c = threadIdx.x;
  inv[c] = 1.0f / (colsum[c] + 1e-5f);
}

// --- outE[k] = acc[k]*inv; T[c] += (acc[k]*inv)[c] * HV[col[k]][c] ----------
__global__ __launch_bounds__(256) void enew_T(
    const float* __restrict__ acc, const float* __restrict__ inv,
    const int* __restrict__ ei, const int* __restrict__ modep,
    const unsigned short* __restrict__ VU,
    float* __restrict__ outE, float* __restrict__ T, int Nn) {
  __shared__ float red[8][256];
  const int c8 = threadIdx.x & 31, sub = threadIdx.x >> 5;
  const int mode = *modep;
  float iv[8];
#pragma unroll
  for (int j = 0; j < 8; ++j) iv[j] = inv[c8 * 8 + j];
  float t[8];
#pragma unroll
  for (int j = 0; j < 8; ++j) t[j] = 0.f;
#pragma unroll 1
  for (int it = 0; it < 8; ++it) {
    const int k = blockIdx.x * 64 + it * 8 + sub;
    const int col = mode ? ei[2 * (Nn + k)] : ei[Nn + k];
    const float4* p0 = reinterpret_cast<const float4*>(acc + (size_t)k * 256 + c8 * 8);
    const float4 a = p0[0], b = p0[1];
    float en[8] = {a.x * iv[0], a.y * iv[1], a.z * iv[2], a.w * iv[3],
                   b.x * iv[4], b.y * iv[5], b.z * iv[6], b.w * iv[7]};
    float4 o0, o1;
    o0.x = en[0]; o0.y = en[1]; o0.z = en[2]; o0.w = en[3];
    o1.x = en[4]; o1.y = en[5]; o1.z = en[6]; o1.w = en[7];
    float4* q0 = reinterpret_cast<float4*>(outE + (size_t)k * 256 + c8 * 8);
    q0[0] = o0; q0[1] = o1;
    const uint4 hv = *reinterpret_cast<const uint4*>(VU + (size_t)col * 512 + c8 * 8);
    const unsigned int w4[4] = {hv.x, hv.y, hv.z, hv.w};
#pragma unroll
    for (int p = 0; p < 4; ++p) {
      t[2 * p] += en[2 * p] * lof(w4[p]);
      t[2 * p + 1] += en[2 * p + 1] * hif(w4[p]);
    }
  }
#pragma unroll
  for (int j = 0; j < 8; ++j) red[sub][c8 * 8 + j] = t[j];
  __syncthreads();
  {
    const int c = threadIdx.x;
    float tt = 0.f;
#pragma unroll
    for (int u2 = 0; u2 < 8; ++u2) tt += red[u2][c];
    atomicAdd(T + c, tt);
  }
}

__global__ __launch_bounds__(256) void hout_k(
    const unsigned short* __restrict__ VU, const float* __restrict__ T,
    float* __restrict__ outH, int nChunks) {
  const int g = blockIdx.x * 256 + threadIdx.x;
  if (g >= nChunks) return;
  const int i = g >> 5, c8 = g & 31;
  const uint4 hu = *reinterpret_cast<const uint4*>(VU + (size_t)i * 512 + 256 + c8 * 8);
  const float4 t0 = *reinterpret_cast<const float4*>(T + c8 * 8);
  const float4 t1 = *reinterpret_cast<const float4*>(T + c8 * 8 + 4);
  float4 o0, o1;
  o0.x = fmaxf(lof(hu.x) + t0.x, 0.f);
  o0.y = fmaxf(hif(hu.x) + t0.y, 0.f);
  o0.z = fmaxf(lof(hu.y) + t0.z, 0.f);
  o0.w = fmaxf(hif(hu.y) + t0.w, 0.f);
  o1.x = fmaxf(lof(hu.z) + t1.x, 0.f);
  o1.y = fmaxf(hif(hu.z) + t1.y, 0.f);
  o1.z = fmaxf(lof(hu.w) + t1.z, 0.f);
  o1.w = fmaxf(hif(hu.w) + t1.w, 0.f);
  float4* q = reinterpret_cast<float4*>(outH + (size_t)i * 256 + c8 * 8);
  q[0] = o0; q[1] = o1;
}

// b1 = [Ab+Db | Bb+Cb], b2 = [Vb | Ub]
__global__ void pack_bias2(const float* a, const float* d, const float* b, const float* cc,
                           const float* v, const float* u,
                           float* b1, float* b2) {
  const int t = threadIdx.x;
  b1[t] = a[t] + d[t];
  b1[256 + t] = b[t] + cc[t];
  b2[t] = v[t];
  b2[256 + t] = u[t];
}

// mode=1 iff edge_index is int64 on device (all high dwords of small values are 0)
__global__ void detect_idx(const int* __restrict__ ei, int* __restrict__ mode) {
  if (threadIdx.x == 0 && blockIdx.x == 0) {
    int m = 0;
#pragma unroll
    for (int i = 1; i < 64; i += 2) m |= ei[i];
    *mode = (m == 0) ? 1 : 0;
  }
}

extern "C" void kernel_launch(void* const* d_in, const int* in_sizes, int n_in,
                              void* d_out, int out_size, void* d_ws, size_t ws_size,
                              hipStream_t stream) {
  const float* h     = (const float*)d_in[0];
  const int*   ei    = (const int*)d_in[1];
  const float* e     = (const float*)d_in[2];
  const float* Aw    = (const float*)d_in[3];
  const float* Ab    = (const float*)d_in[4];
  const float* Bw    = (const float*)d_in[5];
  const float* Bb    = (const float*)d_in[6];
  const float* Cw    = (const float*)d_in[7];
  const float* Cb    = (const float*)d_in[8];
  const float* Dw    = (const float*)d_in[9];
  const float* Db    = (const float*)d_in[10];
  const float* gamma = (const float*)d_in[11];
  const float* beta  = (const float*)d_in[12];
  const float* Uw    = (const float*)d_in[13];
  const float* Ub    = (const float*)d_in[14];
  const float* Vw    = (const float*)d_in[15];
  const float* Vb    = (const float*)d_in[16];
  const int N = in_sizes[0] / 256;  // 131072

  char* ws = (char*)d_ws;
  unsigned short* W1h = (unsigned short*)(ws + 0x0);       // [A;B] tiled, 256 KiB
  unsigned short* W1e = (unsigned short*)(ws + 0x40000);   // [D;C] tiled, 256 KiB
  unsigned short* W2t = (unsigned short*)(ws + 0x80000);   // [V;U] tiled, 256 KiB
  float* b1     = (float*)(ws + 0xC0000);
  float* b2     = (float*)(ws + 0xC0800);
  float* sums   = (float*)(ws + 0xC1000);
  float* sumsq  = (float*)(ws + 0xC1400);
  float* colsum = (float*)(ws + 0xC1800);
  float* Tacc   = (float*)(ws + 0xC1C00);
  float* scale  = (float*)(ws + 0xC2000);
  float* shift  = (float*)(ws + 0xC2400);
  float* inv    = (float*)(ws + 0xC2800);
  int*   mode   = (int*)(ws + 0xC2C00);
  unsigned short* h_t  = (unsigned short*)(ws + 0x100000);   // 64 MiB
  unsigned short* e_t  = (unsigned short*)(ws + 0x4100000);  // 64 MiB
  unsigned short* PRPC = (unsigned short*)(ws + 0x8100000);  // 128 MiB
  unsigned short* VU   = (unsigned short*)(ws + 0x10100000); // 128 MiB
  float*          acc  = (float*)(ws + 0x100000);            // overlays h_t+e_t (dead)
  int* cnt    = (int*)(ws + 0x18100000);
  int* baseA  = (int*)(ws + 0x18180000);
  int* rows_s = (int*)(ws + 0x18210000);
  int* cols_s = (int*)(ws + 0x18290000);
  int* bsum   = (int*)(ws + 0x18310000);

  float* outH = (float*)d_out;
  float* outE = outH + (size_t)N * 256;

  hipMemsetAsync(ws + 0xC1000, 0, 4096, stream);   // sums,sumsq,colsum,Tacc
  hipMemsetAsync(cnt, 0, (size_t)N * 4, stream);
  detect_idx<<<1, 64, 0, stream>>>(ei, mode);
  pack_bias2<<<1, 256, 0, stream>>>(Ab, Db, Bb, Cb, Vb, Ub, b1, b2);
  // weights -> tiled bf16
  prep_tiled<<<32, 256, 0, stream>>>(Aw, W1h, 8192);
  prep_tiled<<<32, 256, 0, stream>>>(Bw, W1h + 16 * 4096, 8192);
  prep_tiled<<<32, 256, 0, stream>>>(Dw, W1e, 8192);
  prep_tiled<<<32, 256, 0, stream>>>(Cw, W1e + 16 * 4096, 8192);
  prep_tiled<<<32, 256, 0, stream>>>(Vw, W2t, 8192);
  prep_tiled<<<32, 256, 0, stream>>>(Uw, W2t + 16 * 4096, 8192);

  // counting sort of edges by row (independent of GEMMs)
  hist_rows<<<N / 256, 256, 0, stream>>>(ei, mode, cnt, N);
  scan1<<<N / 256 / 256 * 256 + ((N / 256) % 256 ? 1 : 0) + 511, 256, 0, stream>>>(cnt, bsum);  // 512 blocks for N=131072
  scan2<<<1, 512, 0, stream>>>(bsum, N / 256);
  scan3<<<N / 256, 256, 0, stream>>>(cnt, bsum, baseA, N);
  scatter_eids<<<N / 256, 256, 0, stream>>>(ei, mode, baseA, cnt, rows_s, cols_s, N);

  const int nChunks = N * 32;
  prep_tiled<<<nChunks / 256, 256, 0, stream>>>(h, h_t, nChunks);
  prep_tiled<<<nChunks / 256, 256, 0, stream>>>(e, e_t, nChunks);
  // GEMM1: PRPC = [h|e] @ [[A|D];[B|C]]^T + b1   (O=512, K=512)
  gemm_bt2<<<(N / 128) * 4, 256, 0, stream>>>(h_t, e_t, W1h, W1e, b1, PRPC, 512, 4, 16, (N / 128) * 4);
  // GEMM2: VU = h @ [V;U]^T + b2                 (O=512, K=256)
  gemm_bt2<<<(N / 128) * 4, 256, 0, stream>>>(h_t, h_t, W2t, W2t, b2, VU, 512, 4, 8, (N / 128) * 4);

  edge_stats<<<N / 64, 256, 0, stream>>>(PRPC, rows_s, cols_s, sums, sumsq);
  bn_finalize<<<1, 256, 0, stream>>>(sums, sumsq, gamma, beta, scale, shift, 1.0f / (float)N);
  gather_sig_colsum<<<N / 64, 256, 0, stream>>>(e, PRPC, baseA, cols_s, scale, shift, acc, colsum);
  inv_finalize<<<1, 256, 0, stream>>>(colsum, inv);
  enew_T<<<N / 64, 256, 0, stream>>>(acc, inv, ei, mode, VU, outE, Tacc, N);
  hout_k<<<nChunks / 256, 256, 0, stream>>>(VU, Tacc, outH, nChunks);
}

// Round 5
// 607.408 us; speedup vs baseline: 2.5680x; 1.0527x over previous
//
#include <hip/hip_runtime.h>
#include <hip/hip_bf16.h>

// ---------------------------------------------------------------------------
// GatedNetwork: N = 131072 nodes == edges, C = 256 channels.
// Algebraic factorization: e_out[k] = PR[row[k]] + PC[col[k]] where
//   PR = h@A^T + e@D^T + (Ab+Db),  PC = h@B^T + e@C^T + (Bb+Cb)
// Pipeline:
//   GEMM1 (two-source K=512): PRPC[i] = [PR|PC]  (bf16, 128 MiB)
//   GEMM2 (K=256):            VU[i]   = [HV|HU]
//   counting-sort edges by row (rows_sorted/cols_sorted)
//   edge_stats: BN batch stats over PR[row]+PC[col]  (batched gathers, MLP)
//   gather: acc[i] = sigmoid(e[i] + sum_seg relu(sc*(PR[i]+PC[col])+sh)) + colsum
//           (scale/shift recomputed per block from sums; LDS cols + prefetch)
//   enew_T: outE = acc*inv; T += acc*inv * HV[col]  (inv computed inline)
//   hout:   outH = relu(HU + T)
// ---------------------------------------------------------------------------

typedef __attribute__((ext_vector_type(8))) short bf16x8;
typedef __attribute__((ext_vector_type(4))) float f32x4;

__device__ __forceinline__ float b2f(unsigned int lo16) {
  union { unsigned int u; float f; } c; c.u = lo16 << 16; return c.f;
}
__device__ __forceinline__ float lof(unsigned int u) { return b2f(u & 0xffffu); }
__device__ __forceinline__ float hif(unsigned int u) { return b2f(u >> 16); }
__device__ __forceinline__ unsigned int f2b(float f) {  // RNE f32->bf16
  union { float f; unsigned int u; } c; c.f = f;
  unsigned int u = c.u;
  u += 0x7fffu + ((u >> 16) & 1u);
  return u >> 16;
}

// --- prep: f32 row-major [M][256] -> bf16 tiled [M/16][32][16][8] ----------
__device__ __forceinline__ void prep_chunk(const float* __restrict__ src,
                                           unsigned short* __restrict__ dst, int g) {
  int mtile = g >> 9;
  int rem = g & 511;
  int r = rem >> 5, k8 = rem & 31;
  const float4* s = reinterpret_cast<const float4*>(src + (((size_t)mtile * 16 + r) << 8) + k8 * 8);
  float4 v0 = s[0], v1 = s[1];
  uint4 o;
  o.x = f2b(v0.x) | (f2b(v0.y) << 16);
  o.y = f2b(v0.z) | (f2b(v0.w) << 16);
  o.z = f2b(v1.x) | (f2b(v1.y) << 16);
  o.w = f2b(v1.z) | (f2b(v1.w) << 16);
  *reinterpret_cast<uint4*>(dst + ((size_t)mtile * 512 + k8 * 16 + r) * 8) = o;
}

// one launch: h -> h_t and e -> e_t (nChunksEach per source)
__global__ __launch_bounds__(256) void prep_he(const float* __restrict__ h,
                                               unsigned short* __restrict__ h_t,
                                               const float* __restrict__ e,
                                               unsigned short* __restrict__ e_t,
                                               int nChunksEach) {
  int g = blockIdx.x * 256 + threadIdx.x;
  if (g < nChunksEach) prep_chunk(h, h_t, g);
  else if (g < 2 * nChunksEach) prep_chunk(e, e_t, g - nChunksEach);
}

// one launch: all six 256x256 weights -> tiled bf16 (8192 chunks each)
__global__ __launch_bounds__(256) void prep_weights(
    const float* __restrict__ s0, const float* __restrict__ s1,
    const float* __restrict__ s2, const float* __restrict__ s3,
    const float* __restrict__ s4, const float* __restrict__ s5,
    unsigned short* __restrict__ W1h, unsigned short* __restrict__ W1e,
    unsigned short* __restrict__ W2t) {
  int g = blockIdx.x * 256 + threadIdx.x;
  int sel = g >> 13;
  int gg = g & 8191;
  const float* src; unsigned short* dst;
  switch (sel) {
    case 0: src = s0; dst = W1h; break;           // A
    case 1: src = s1; dst = W1h + 65536; break;   // B
    case 2: src = s2; dst = W1e; break;           // D
    case 3: src = s3; dst = W1e + 65536; break;   // C
    case 4: src = s4; dst = W2t; break;           // V
    default: src = s5; dst = W2t + 65536; break;  // U
  }
  prep_chunk(src, dst, gg);
}

// --- GEMM (two K-sources): C[m][o] = sum_k Ah[m][k]Bh[o][k] (+ Ae*Be) + bias
__global__ __launch_bounds__(256) void gemm_bt2(
    const unsigned short* __restrict__ Ah, const unsigned short* __restrict__ Ae,
    const unsigned short* __restrict__ Bh, const unsigned short* __restrict__ Be,
    const float* __restrict__ bias, unsigned short* __restrict__ Cmat,
    int O, int nColBlk, int ktSteps, int nBlk) {
  __shared__ char lds[16384];
  const int cpx = nBlk >> 3;
  const int hw = blockIdx.x;
  const int bid = (hw % 8) * cpx + hw / 8;  // bijective XCD swizzle (nBlk%8==0)
  const int colBlk = bid % nColBlk;
  const int rowBlk = bid / nColBlk;
  const int tid = threadIdx.x;
  const int w = tid >> 6, lane = tid & 63;
  const int wm = w >> 1, wn = w & 1;

  const size_t aTileOff = (size_t)(rowBlk * 8 + w * 2) * 8192 + lane * 16;
  const size_t bTileOff = (size_t)(colBlk * 8 + w * 2) * 8192 + lane * 16;
  char* ldsA0 = lds + (w * 2) * 1024;
  char* ldsA1 = lds + (w * 2 + 1) * 1024;
  char* ldsB0 = lds + 8192 + (w * 2) * 1024;
  char* ldsB1 = lds + 8192 + (w * 2 + 1) * 1024;

  f32x4 acc[4][4] = {};

  for (int kt = 0; kt < ktSteps; ++kt) {
    const char* Abase = (const char*)(kt < 8 ? Ah : Ae) + aTileOff + (size_t)(kt & 7) * 1024;
    const char* Bbase = (const char*)(kt < 8 ? Bh : Be) + bTileOff + (size_t)(kt & 7) * 1024;
    __builtin_amdgcn_global_load_lds((const __attribute__((address_space(1))) void*)Abase,
                                     (__attribute__((address_space(3))) void*)ldsA0, 16, 0, 0);
    __builtin_amdgcn_global_load_lds((const __attribute__((address_space(1))) void*)(Abase + 8192),
                                     (__attribute__((address_space(3))) void*)ldsA1, 16, 0, 0);
    __builtin_amdgcn_global_load_lds((const __attribute__((address_space(1))) void*)Bbase,
                                     (__attribute__((address_space(3))) void*)ldsB0, 16, 0, 0);
    __builtin_amdgcn_global_load_lds((const __attribute__((address_space(1))) void*)(Bbase + 8192),
                                     (__attribute__((address_space(3))) void*)ldsB1, 16, 0, 0);
    __syncthreads();
    bf16x8 a[4], b[4];
#pragma unroll
    for (int mi = 0; mi < 4; ++mi)
      a[mi] = *reinterpret_cast<const bf16x8*>(lds + (wm * 4 + mi) * 1024 + lane * 16);
#pragma unroll
    for (int ni = 0; ni < 4; ++ni)
      b[ni] = *reinterpret_cast<const bf16x8*>(lds + 8192 + (wn * 4 + ni) * 1024 + lane * 16);
#pragma unroll
    for (int mi = 0; mi < 4; ++mi)
#pragma unroll
      for (int ni = 0; ni < 4; ++ni)
        acc[mi][ni] = __builtin_amdgcn_mfma_f32_16x16x32_bf16(a[mi], b[ni], acc[mi][ni], 0, 0, 0);
    __syncthreads();
  }

  const int rb = rowBlk * 128 + wm * 64 + ((lane >> 4) << 2);
  const int cb = colBlk * 128 + wn * 64 + (lane & 15);
#pragma unroll
  for (int mi = 0; mi < 4; ++mi) {
#pragma unroll
    for (int ni = 0; ni < 4; ++ni) {
      const int coln = cb + ni * 16;
      const float bz = bias[coln];
      const size_t base = (size_t)(rb + mi * 16) * O + coln;
#pragma unroll
      for (int r = 0; r < 4; ++r)
        Cmat[base + (size_t)r * O] = (unsigned short)f2b(acc[mi][ni][r] + bz);
    }
  }
}

// --- BN batch stats over e_out[p] = PR[rows_s[p]] + PC[cols_s[p]] ----------
// Batched: preload 4 index pairs, issue 8 independent row-gathers, consume.
__global__ __launch_bounds__(256) void edge_stats(
    const unsigned short* __restrict__ PRPC,
    const int* __restrict__ rows_s, const int* __restrict__ cols_s,
    float* __restrict__ sums, float* __restrict__ sumsq) {
  __shared__ float red[8][256];
  const int c8 = threadIdx.x & 31;
  const int sub = threadIdx.x >> 5;
  float s[8], q[8];
#pragma unroll
  for (int j = 0; j < 8; ++j) { s[j] = 0.f; q[j] = 0.f; }
#pragma unroll 1
  for (int grp = 0; grp < 2; ++grp) {
    const int kb = blockIdx.x * 64 + grp * 32 + sub * 4;
    int r[4], cj[4];
#pragma unroll
    for (int u = 0; u < 4; ++u) { r[u] = rows_s[kb + u]; cj[u] = cols_s[kb + u]; }
    uint4 pr[4], pc[4];
#pragma unroll
    for (int u = 0; u < 4; ++u)
      pr[u] = *reinterpret_cast<const uint4*>(PRPC + (size_t)r[u] * 512 + c8 * 8);
#pragma unroll
    for (int u = 0; u < 4; ++u)
      pc[u] = *reinterpret_cast<const uint4*>(PRPC + (size_t)cj[u] * 512 + 256 + c8 * 8);
#pragma unroll
    for (int u = 0; u < 4; ++u) {
      const unsigned int rw[4] = {pr[u].x, pr[u].y, pr[u].z, pr[u].w};
      const unsigned int cw[4] = {pc[u].x, pc[u].y, pc[u].z, pc[u].w};
#pragma unroll
      for (int p4 = 0; p4 < 4; ++p4) {
        const float v0 = lof(rw[p4]) + lof(cw[p4]);
        const float v1 = hif(rw[p4]) + hif(cw[p4]);
        s[2 * p4] += v0;     q[2 * p4] += v0 * v0;
        s[2 * p4 + 1] += v1; q[2 * p4 + 1] += v1 * v1;
      }
    }
  }
#pragma unroll
  for (int j = 0; j < 8; ++j) red[sub][c8 * 8 + j] = s[j];
  __syncthreads();
  {
    const int c = threadIdx.x;
    float t = 0.f;
#pragma unroll
    for (int u2 = 0; u2 < 8; ++u2) t += red[u2][c];
    atomicAdd(sums + c, t);
  }
  __syncthreads();
#pragma unroll
  for (int j = 0; j < 8; ++j) red[sub][c8 * 8 + j] = q[j];
  __syncthreads();
  {
    const int c = threadIdx.x;
    float t = 0.f;
#pragma unroll
    for (int u2 = 0; u2 < 8; ++u2) t += red[u2][c];
    atomicAdd(sumsq + c, t);
  }
}

// --- counting sort of edges by row -----------------------------------------
__global__ __launch_bounds__(256) void hist_rows(const int* __restrict__ ei,
                                                 const int* __restrict__ modep,
                                                 int* __restrict__ cnt, int Nn) {
  const int k = blockIdx.x * 256 + threadIdx.x;
  if (k >= Nn) return;
  const int row = (*modep) ? ei[2 * k] : ei[k];
  atomicAdd(&cnt[row], 1);
}

__global__ __launch_bounds__(256) void scan1(const int* __restrict__ cnt,
                                             int* __restrict__ bsum) {
  __shared__ int red[256];
  const int t = threadIdx.x;
  red[t] = cnt[blockIdx.x * 256 + t];
  __syncthreads();
#pragma unroll
  for (int s = 128; s > 0; s >>= 1) {
    if (t < s) red[t] += red[t + s];
    __syncthreads();
  }
  if (t == 0) bsum[blockIdx.x] = red[0];
}

__global__ __launch_bounds__(512) void scan2(int* __restrict__ bsum, int nb) {
  __shared__ int tmp[512];
  const int t = threadIdx.x;
  const int own = (t < nb) ? bsum[t] : 0;
  tmp[t] = own;
  __syncthreads();
  for (int off = 1; off < 512; off <<= 1) {
    int v = (t >= off) ? tmp[t - off] : 0;
    __syncthreads();
    tmp[t] += v;
    __syncthreads();
  }
  if (t < nb) bsum[t] = tmp[t] - own;  // exclusive
}

__global__ __launch_bounds__(256) void scan3(const int* __restrict__ cnt,
                                             const int* __restrict__ bsum,
                                             int* __restrict__ base, int Nn) {
  __shared__ int tmp[256];
  const int t = threadIdx.x;
  const int gid = blockIdx.x * 256 + t;
  const int own = cnt[gid];
  tmp[t] = own;
  __syncthreads();
  for (int off = 1; off < 256; off <<= 1) {
    int v = (t >= off) ? tmp[t - off] : 0;
    __syncthreads();
    tmp[t] += v;
    __syncthreads();
  }
  base[gid] = tmp[t] - own + bsum[blockIdx.x];
  if (gid == 0) base[Nn] = Nn;  // E == N
}

__global__ __launch_bounds__(256) void scatter_eids(const int* __restrict__ ei,
                                                    const int* __restrict__ modep,
                                                    const int* __restrict__ base,
                                                    int* __restrict__ cnt,
                                                    int* __restrict__ rows_s,
                                                    int* __restrict__ cols_s, int Nn) {
  const int k = blockIdx.x * 256 + threadIdx.x;
  if (k >= Nn) return;
  int row, col;
  if (*modep) { row = ei[2 * k]; col = ei[2 * (Nn + k)]; }
  else        { row = ei[k];     col = ei[Nn + k]; }
  const int pos = base[row] + atomicAdd(&cnt[row], -1) - 1;
  rows_s[pos] = row;
  cols_s[pos] = col;
}

// --- fused: acc[i] = sigmoid(e[i] + sum_seg relu(sc*(PR[i]+PC[col])+sh)) ----
// scale/shift recomputed per block (sums/sumsq L2-hot); cols staged in LDS;
// 1-deep software prefetch of the next PC row across node boundaries.
#define GCAP 1024
__global__ __launch_bounds__(256) void gather_sig_colsum(
    const float* __restrict__ e, const unsigned short* __restrict__ PRPC,
    const int* __restrict__ base, const int* __restrict__ cols_s,
    const float* __restrict__ sums, const float* __restrict__ sumsq,
    const float* __restrict__ gamma, const float* __restrict__ beta,
    float* __restrict__ acc, float* __restrict__ colsum, float invE) {
  __shared__ float red[4][256];
  __shared__ int colsL[GCAP];
  __shared__ int baseL[65];
  const int lane = threadIdx.x & 63, w = threadIdx.x >> 6;
  const int n0 = blockIdx.x * 64;
  if (threadIdx.x < 65) baseL[threadIdx.x] = base[n0 + threadIdx.x];
  __syncthreads();
  const int bstart = baseL[0];
  const int bcount = baseL[64] - bstart;
  for (int qq = threadIdx.x; qq < bcount && qq < GCAP; qq += 256)
    colsL[qq] = cols_s[bstart + qq];
  // per-lane BN scale/shift for channels lane*4..lane*4+3
  const float4 sm = *reinterpret_cast<const float4*>(sums + lane * 4);
  const float4 sq = *reinterpret_cast<const float4*>(sumsq + lane * 4);
  const float4 gm = *reinterpret_cast<const float4*>(gamma + lane * 4);
  const float4 bt = *reinterpret_cast<const float4*>(beta + lane * 4);
  float4 sc, sh;
  {
    const float mx = sm.x * invE, my = sm.y * invE, mz = sm.z * invE, mw = sm.w * invE;
    sc.x = gm.x * rsqrtf(fmaxf(sq.x * invE - mx * mx, 0.f) + 1e-5f);
    sc.y = gm.y * rsqrtf(fmaxf(sq.y * invE - my * my, 0.f) + 1e-5f);
    sc.z = gm.z * rsqrtf(fmaxf(sq.z * invE - mz * mz, 0.f) + 1e-5f);
    sc.w = gm.w * rsqrtf(fmaxf(sq.w * invE - mw * mw, 0.f) + 1e-5f);
    sh.x = bt.x - mx * sc.x; sh.y = bt.y - my * sc.y;
    sh.z = bt.z - mz * sc.z; sh.w = bt.w - mw * sc.w;
  }
  __syncthreads();
  float s0 = 0.f, s1 = 0.f, s2 = 0.f, s3 = 0.f;
  const int i0 = n0 + w * 16;
  int p = baseL[w * 16];
  const int pendW = baseL[w * 16 + 16];
  uint2 pcn;
  pcn.x = 0; pcn.y = 0;
  if (p < pendW) {
    const int q0 = p - bstart;
    const int cj = (q0 < GCAP) ? colsL[q0] : cols_s[p];
    pcn = *reinterpret_cast<const uint2*>(PRPC + (size_t)cj * 512 + 256 + lane * 4);
  }
  float4 ev = *reinterpret_cast<const float4*>(e + (size_t)i0 * 256 + lane * 4);
  uint2 prv = *reinterpret_cast<const uint2*>(PRPC + (size_t)i0 * 512 + lane * 4);
#pragma unroll 1
  for (int it = 0; it < 16; ++it) {
    float4 v = ev;
    const uint2 pr = prv;
    if (it + 1 < 16) {
      ev = *reinterpret_cast<const float4*>(e + (size_t)(i0 + it + 1) * 256 + lane * 4);
      prv = *reinterpret_cast<const uint2*>(PRPC + (size_t)(i0 + it + 1) * 512 + lane * 4);
    }
    const float pr0 = lof(pr.x), pr1 = hif(pr.x), pr2 = lof(pr.y), pr3 = hif(pr.y);
    const int pe = baseL[w * 16 + it + 1];
#pragma unroll 1
    while (p < pe) {
      const uint2 pc = pcn;
      if (p + 1 < pendW) {
        const int qn = p + 1 - bstart;
        const int cj = (qn < GCAP) ? colsL[qn] : cols_s[p + 1];
        pcn = *reinterpret_cast<const uint2*>(PRPC + (size_t)cj * 512 + 256 + lane * 4);
      }
      v.x += fmaxf(fmaf(sc.x, pr0 + lof(pc.x), sh.x), 0.f);
      v.y += fmaxf(fmaf(sc.y, pr1 + hif(pc.x), sh.y), 0.f);
      v.z += fmaxf(fmaf(sc.z, pr2 + lof(pc.y), sh.z), 0.f);
      v.w += fmaxf(fmaf(sc.w, pr3 + hif(pc.y), sh.w), 0.f);
      ++p;
    }
    v.x = 1.f / (1.f + __expf(-v.x));
    v.y = 1.f / (1.f + __expf(-v.y));
    v.z = 1.f / (1.f + __expf(-v.z));
    v.w = 1.f / (1.f + __expf(-v.w));
    *reinterpret_cast<float4*>(acc + (size_t)(i0 + it) * 256 + lane * 4) = v;
    s0 += v.x; s1 += v.y; s2 += v.z; s3 += v.w;
  }
  red[w][lane * 4 + 0] = s0;
  red[w][lane * 4 + 1] = s1;
  red[w][lane * 4 + 2] = s2;
  red[w][lane * 4 + 3] = s3;
  __syncthreads();
  const int c = threadIdx.x;
  atomicAdd(colsum + c, red[0][c] + red[1][c] + red[2][c] + red[3][c]);
}

// --- outE[k] = acc[k]*inv; T[c] += (acc[k]*inv)[c] * HV[col[k]][c] ----------
// inv computed inline from colsum; batched VU gathers (4 in flight).
__global__ __launch_bounds__(256) void enew_T(
    const float* __restrict__ acc, const float* __restrict__ colsum,
    const int* __restrict__ ei, const int* __restrict__ modep,
    const unsigned short* __restrict__ VU,
    float* __restrict__ outE, float* __restrict__ T, int Nn) {
  __shared__ float red[8][256];
  const int c8 = threadIdx.x & 31, sub = threadIdx.x >> 5;
  const int mode = *modep;
  float iv[8];
#pragma unroll
  for (int j = 0; j < 8; ++j) iv[j] = 1.0f / (colsum[c8 * 8 + j] + 1e-5f);
  float t[8];
#pragma unroll
  for (int j = 0; j < 8; ++j) t[j] = 0.f;
#pragma unroll 1
  for (int grp = 0; grp < 2; ++grp) {
    const int kb = blockIdx.x * 64 + grp * 32 + sub * 4;
    int col[4];
#pragma unroll
    for (int u = 0; u < 4; ++u)
      col[u] = mode ? ei[2 * (Nn + kb + u)] : ei[Nn + kb + u];
    uint4 hv[4];
#pragma unroll
    for (int u = 0; u < 4; ++u)
      hv[u] = *reinterpret_cast<const uint4*>(VU + (size_t)col[u] * 512 + c8 * 8);
    float4 a[4], b[4];
#pragma unroll
    for (int u = 0; u < 4; ++u) {
      const float4* p0 = reinterpret_cast<const float4*>(acc + (size_t)(kb + u) * 256 + c8 * 8);
      a[u] = p0[0]; b[u] = p0[1];
    }
#pragma unroll
    for (int u = 0; u < 4; ++u) {
      float en[8] = {a[u].x * iv[0], a[u].y * iv[1], a[u].z * iv[2], a[u].w * iv[3],
                     b[u].x * iv[4], b[u].y * iv[5], b[u].z * iv[6], b[u].w * iv[7]};
      float4 o0, o1;
      o0.x = en[0]; o0.y = en[1]; o0.z = en[2]; o0.w = en[3];
      o1.x = en[4]; o1.y = en[5]; o1.z = en[6]; o1.w = en[7];
      float4* q0 = reinterpret_cast<float4*>(outE + (size_t)(kb + u) * 256 + c8 * 8);
      q0[0] = o0; q0[1] = o1;
      const unsigned int w4[4] = {hv[u].x, hv[u].y, hv[u].z, hv[u].w};
#pragma unroll
      for (int p = 0; p < 4; ++p) {
        t[2 * p] += en[2 * p] * lof(w4[p]);
        t[2 * p + 1] += en[2 * p + 1] * hif(w4[p]);
      }
    }
  }
#pragma unroll
  for (int j = 0; j < 8; ++j) red[sub][c8 * 8 + j] = t[j];
  __syncthreads();
  {
    const int c = threadIdx.x;
    float tt = 0.f;
#pragma unroll
    for (int u2 = 0; u2 < 8; ++u2) tt += red[u2][c];
    atomicAdd(T + c, tt);
  }
}

__global__ __launch_bounds__(256) void hout_k(
    const unsigned short* __restrict__ VU, const float* __restrict__ T,
    float* __restrict__ outH, int nChunks) {
  const int g = blockIdx.x * 256 + threadIdx.x;
  if (g >= nChunks) return;
  const int i = g >> 5, c8 = g & 31;
  const uint4 hu = *reinterpret_cast<const uint4*>(VU + (size_t)i * 512 + 256 + c8 * 8);
  const float4 t0 = *reinterpret_cast<const float4*>(T + c8 * 8);
  const float4 t1 = *reinterpret_cast<const float4*>(T + c8 * 8 + 4);
  float4 o0, o1;
  o0.x = fmaxf(lof(hu.x) + t0.x, 0.f);
  o0.y = fmaxf(hif(hu.x) + t0.y, 0.f);
  o0.z = fmaxf(lof(hu.y) + t0.z, 0.f);
  o0.w = fmaxf(hif(hu.y) + t0.w, 0.f);
  o1.x = fmaxf(lof(hu.z) + t1.x, 0.f);
  o1.y = fmaxf(hif(hu.z) + t1.y, 0.f);
  o1.z = fmaxf(lof(hu.w) + t1.z, 0.f);
  o1.w = fmaxf(hif(hu.w) + t1.w, 0.f);
  float4* q = reinterpret_cast<float4*>(outH + (size_t)i * 256 + c8 * 8);
  q[0] = o0; q[1] = o1;
}

// b1 = [Ab+Db | Bb+Cb], b2 = [Vb | Ub]
__global__ void pack_bias2(const float* a, const float* d, const float* b, const float* cc,
                           const float* v, const float* u,
                           float* b1, float* b2) {
  const int t = threadIdx.x;
  b1[t] = a[t] + d[t];
  b1[256 + t] = b[t] + cc[t];
  b2[t] = v[t];
  b2[256 + t] = u[t];
}

// mode=1 iff edge_index is int64 on device (all high dwords of small values are 0)
__global__ void detect_idx(const int* __restrict__ ei, int* __restrict__ mode) {
  if (threadIdx.x == 0 && blockIdx.x == 0) {
    int m = 0;
#pragma unroll
    for (int i = 1; i < 64; i += 2) m |= ei[i];
    *mode = (m == 0) ? 1 : 0;
  }
}

extern "C" void kernel_launch(void* const* d_in, const int* in_sizes, int n_in,
                              void* d_out, int out_size, void* d_ws, size_t ws_size,
                              hipStream_t stream) {
  const float* h     = (const float*)d_in[0];
  const int*   ei    = (const int*)d_in[1];
  const float* e     = (const float*)d_in[2];
  const float* Aw    = (const float*)d_in[3];
  const float* Ab    = (const float*)d_in[4];
  const float* Bw    = (const float*)d_in[5];
  const float* Bb    = (const float*)d_in[6];
  const float* Cw    = (const float*)d_in[7];
  const float* Cb    = (const float*)d_in[8];
  const float* Dw    = (const float*)d_in[9];
  const float* Db    = (const float*)d_in[10];
  const float* gamma = (const float*)d_in[11];
  const float* beta  = (const float*)d_in[12];
  const float* Uw    = (const float*)d_in[13];
  const float* Ub    = (const float*)d_in[14];
  const float* Vw    = (const float*)d_in[15];
  const float* Vb    = (const float*)d_in[16];
  const int N = in_sizes[0] / 256;  // 131072

  char* ws = (char*)d_ws;
  unsigned short* W1h = (unsigned short*)(ws + 0x0);       // [A;B] tiled, 256 KiB
  unsigned short* W1e = (unsigned short*)(ws + 0x40000);   // [D;C] tiled, 256 KiB
  unsigned short* W2t = (unsigned short*)(ws + 0x80000);   // [V;U] tiled, 256 KiB
  float* b1     = (float*)(ws + 0xC0000);
  float* b2     = (float*)(ws + 0xC0800);
  float* sums   = (float*)(ws + 0xC1000);
  float* sumsq  = (float*)(ws + 0xC1400);
  float* colsum = (float*)(ws + 0xC1800);
  float* Tacc   = (float*)(ws + 0xC1C00);
  int*   mode   = (int*)(ws + 0xC2C00);
  unsigned short* h_t  = (unsigned short*)(ws + 0x100000);   // 64 MiB
  unsigned short* e_t  = (unsigned short*)(ws + 0x4100000);  // 64 MiB
  unsigned short* PRPC = (unsigned short*)(ws + 0x8100000);  // 128 MiB
  unsigned short* VU   = (unsigned short*)(ws + 0x10100000); // 128 MiB
  float*          acc  = (float*)(ws + 0x100000);            // overlays h_t+e_t (dead)
  int* cnt    = (int*)(ws + 0x18100000);
  int* baseA  = (int*)(ws + 0x18180000);
  int* rows_s = (int*)(ws + 0x18210000);
  int* cols_s = (int*)(ws + 0x18290000);
  int* bsum   = (int*)(ws + 0x18310000);

  float* outH = (float*)d_out;
  float* outE = outH + (size_t)N * 256;

  hipMemsetAsync(ws + 0xC1000, 0, 4096, stream);   // sums,sumsq,colsum,Tacc
  hipMemsetAsync(cnt, 0, (size_t)N * 4, stream);
  detect_idx<<<1, 64, 0, stream>>>(ei, mode);
  pack_bias2<<<1, 256, 0, stream>>>(Ab, Db, Bb, Cb, Vb, Ub, b1, b2);
  prep_weights<<<192, 256, 0, stream>>>(Aw, Bw, Dw, Cw, Vw, Uw, W1h, W1e, W2t);

  // counting sort of edges by row
  hist_rows<<<N / 256, 256, 0, stream>>>(ei, mode, cnt, N);
  scan1<<<N / 256, 256, 0, stream>>>(cnt, bsum);          // 512 blocks @ N=131072
  scan2<<<1, 512, 0, stream>>>(bsum, N / 256);            // nb = 512
  scan3<<<N / 256, 256, 0, stream>>>(cnt, bsum, baseA, N);
  scatter_eids<<<N / 256, 256, 0, stream>>>(ei, mode, baseA, cnt, rows_s, cols_s, N);

  const int nChunks = N * 32;
  prep_he<<<2 * nChunks / 256, 256, 0, stream>>>(h, h_t, e, e_t, nChunks);
  // GEMM1: PRPC = [h|e] @ [[A|D];[B|C]]^T + b1   (O=512, K=512)
  gemm_bt2<<<(N / 128) * 4, 256, 0, stream>>>(h_t, e_t, W1h, W1e, b1, PRPC, 512, 4, 16, (N / 128) * 4);
  // GEMM2: VU = h @ [V;U]^T + b2                 (O=512, K=256)
  gemm_bt2<<<(N / 128) * 4, 256, 0, stream>>>(h_t, h_t, W2t, W2t, b2, VU, 512, 4, 8, (N / 128) * 4);

  edge_stats<<<N / 64, 256, 0, stream>>>(PRPC, rows_s, cols_s, sums, sumsq);
  gather_sig_colsum<<<N / 64, 256, 0, stream>>>(e, PRPC, baseA, cols_s, sums, sumsq,
                                                gamma, beta, acc, colsum, 1.0f / (float)N);
  enew_T<<<N / 64, 256, 0, stream>>>(acc, colsum, ei, mode, VU, outE, Tacc, N);
  hout_k<<<nChunks / 256, 256, 0, stream>>>(VU, Tacc, outH, nChunks);
}

// Round 6
// 574.124 us; speedup vs baseline: 2.7169x; 1.0580x over previous
//
#include <hip/hip_runtime.h>
#include <hip/hip_bf16.h>

// ---------------------------------------------------------------------------
// GatedNetwork: N = 131072 nodes == edges, C = 256 channels.
// Factorization: e_out[k] = PR[row[k]] + PC[col[k]],
//   PR = h@A^T + e@D^T + (Ab+Db),  PC = h@B^T + e@C^T + (Bb+Cb)
// Pipeline (13 dispatches):
//   prep_weights(+bias,+idx-mode) | sort(hist,scan1,scan2,scan3,scatter)
//   prep_he | GEMM1 PRPC | GEMM2 VU
//   edge_stats (BN batch stats, gathered)
//   gather_sig_T: sig=sigmoid(e + sum_seg BNReLU(PR+PC)) -> accB (bf16),
//                 colsum += sig, Traw += sig * HV[col]  (VU gathered in-pass)
//   finalize: outE = accB*iv ; outH = relu(HU + iv*Traw)
// ---------------------------------------------------------------------------

typedef __attribute__((ext_vector_type(8))) short bf16x8;
typedef __attribute__((ext_vector_type(4))) float f32x4;

__device__ __forceinline__ float b2f(unsigned int lo16) {
  union { unsigned int u; float f; } c; c.u = lo16 << 16; return c.f;
}
__device__ __forceinline__ float lof(unsigned int u) { return b2f(u & 0xffffu); }
__device__ __forceinline__ float hif(unsigned int u) { return b2f(u >> 16); }
__device__ __forceinline__ unsigned int f2b(float f) {  // RNE f32->bf16
  union { float f; unsigned int u; } c; c.f = f;
  unsigned int u = c.u;
  u += 0x7fffu + ((u >> 16) & 1u);
  return u >> 16;
}

// --- prep: f32 row-major [M][256] -> bf16 tiled [M/16][32][16][8] ----------
__device__ __forceinline__ void prep_chunk(const float* __restrict__ src,
                                           unsigned short* __restrict__ dst, int g) {
  int mtile = g >> 9;
  int rem = g & 511;
  int r = rem >> 5, k8 = rem & 31;
  const float4* s = reinterpret_cast<const float4*>(src + (((size_t)mtile * 16 + r) << 8) + k8 * 8);
  float4 v0 = s[0], v1 = s[1];
  uint4 o;
  o.x = f2b(v0.x) | (f2b(v0.y) << 16);
  o.y = f2b(v0.z) | (f2b(v0.w) << 16);
  o.z = f2b(v1.x) | (f2b(v1.y) << 16);
  o.w = f2b(v1.z) | (f2b(v1.w) << 16);
  *reinterpret_cast<uint4*>(dst + ((size_t)mtile * 512 + k8 * 16 + r) * 8) = o;
}

__global__ __launch_bounds__(256) void prep_he(const float* __restrict__ h,
                                               unsigned short* __restrict__ h_t,
                                               const float* __restrict__ e,
                                               unsigned short* __restrict__ e_t,
                                               int nChunksEach) {
  int g = blockIdx.x * 256 + threadIdx.x;
  if (g < nChunksEach) prep_chunk(h, h_t, g);
  else if (g < 2 * nChunksEach) prep_chunk(e, e_t, g - nChunksEach);
}

// all six weights -> tiled bf16; block 0 also packs biases + detects idx mode
__global__ __launch_bounds__(256) void prep_weights(
    const float* __restrict__ s0, const float* __restrict__ s1,
    const float* __restrict__ s2, const float* __restrict__ s3,
    const float* __restrict__ s4, const float* __restrict__ s5,
    unsigned short* __restrict__ W1h, unsigned short* __restrict__ W1e,
    unsigned short* __restrict__ W2t,
    const float* __restrict__ Ab, const float* __restrict__ Db,
    const float* __restrict__ Bb, const float* __restrict__ Cb,
    const float* __restrict__ Vb, const float* __restrict__ Ub,
    float* __restrict__ b1, float* __restrict__ b2,
    const int* __restrict__ ei, int* __restrict__ mode) {
  int g = blockIdx.x * 256 + threadIdx.x;
  if (blockIdx.x == 0) {
    const int t = threadIdx.x;
    b1[t] = Ab[t] + Db[t];
    b1[256 + t] = Bb[t] + Cb[t];
    b2[t] = Vb[t];
    b2[256 + t] = Ub[t];
    if (t == 0) {
      int m = 0;
#pragma unroll
      for (int i = 1; i < 64; i += 2) m |= ei[i];
      *mode = (m == 0) ? 1 : 0;
    }
  }
  int sel = g >> 13;
  int gg = g & 8191;
  const float* src; unsigned short* dst;
  switch (sel) {
    case 0: src = s0; dst = W1h; break;           // A
    case 1: src = s1; dst = W1h + 65536; break;   // B
    case 2: src = s2; dst = W1e; break;           // D
    case 3: src = s3; dst = W1e + 65536; break;   // C
    case 4: src = s4; dst = W2t; break;           // V
    default: src = s5; dst = W2t + 65536; break;  // U
  }
  prep_chunk(src, dst, gg);
}

// --- GEMM (two K-sources): C[m][o] = sum_k Ah[m][k]Bh[o][k] (+ Ae*Be) + bias
__global__ __launch_bounds__(256) void gemm_bt2(
    const unsigned short* __restrict__ Ah, const unsigned short* __restrict__ Ae,
    const unsigned short* __restrict__ Bh, const unsigned short* __restrict__ Be,
    const float* __restrict__ bias, unsigned short* __restrict__ Cmat,
    int O, int nColBlk, int ktSteps, int nBlk) {
  __shared__ char lds[16384];
  const int cpx = nBlk >> 3;
  const int hw = blockIdx.x;
  const int bid = (hw % 8) * cpx + hw / 8;  // bijective XCD swizzle (nBlk%8==0)
  const int colBlk = bid % nColBlk;
  const int rowBlk = bid / nColBlk;
  const int tid = threadIdx.x;
  const int w = tid >> 6, lane = tid & 63;
  const int wm = w >> 1, wn = w & 1;

  const size_t aTileOff = (size_t)(rowBlk * 8 + w * 2) * 8192 + lane * 16;
  const size_t bTileOff = (size_t)(colBlk * 8 + w * 2) * 8192 + lane * 16;
  char* ldsA0 = lds + (w * 2) * 1024;
  char* ldsA1 = lds + (w * 2 + 1) * 1024;
  char* ldsB0 = lds + 8192 + (w * 2) * 1024;
  char* ldsB1 = lds + 8192 + (w * 2 + 1) * 1024;

  f32x4 acc[4][4] = {};

  for (int kt = 0; kt < ktSteps; ++kt) {
    const char* Abase = (const char*)(kt < 8 ? Ah : Ae) + aTileOff + (size_t)(kt & 7) * 1024;
    const char* Bbase = (const char*)(kt < 8 ? Bh : Be) + bTileOff + (size_t)(kt & 7) * 1024;
    __builtin_amdgcn_global_load_lds((const __attribute__((address_space(1))) void*)Abase,
                                     (__attribute__((address_space(3))) void*)ldsA0, 16, 0, 0);
    __builtin_amdgcn_global_load_lds((const __attribute__((address_space(1))) void*)(Abase + 8192),
                                     (__attribute__((address_space(3))) void*)ldsA1, 16, 0, 0);
    __builtin_amdgcn_global_load_lds((const __attribute__((address_space(1))) void*)Bbase,
                                     (__attribute__((address_space(3))) void*)ldsB0, 16, 0, 0);
    __builtin_amdgcn_global_load_lds((const __attribute__((address_space(1))) void*)(Bbase + 8192),
                                     (__attribute__((address_space(3))) void*)ldsB1, 16, 0, 0);
    __syncthreads();
    bf16x8 a[4], b[4];
#pragma unroll
    for (int mi = 0; mi < 4; ++mi)
      a[mi] = *reinterpret_cast<const bf16x8*>(lds + (wm * 4 + mi) * 1024 + lane * 16);
#pragma unroll
    for (int ni = 0; ni < 4; ++ni)
      b[ni] = *reinterpret_cast<const bf16x8*>(lds + 8192 + (wn * 4 + ni) * 1024 + lane * 16);
#pragma unroll
    for (int mi = 0; mi < 4; ++mi)
#pragma unroll
      for (int ni = 0; ni < 4; ++ni)
        acc[mi][ni] = __builtin_amdgcn_mfma_f32_16x16x32_bf16(a[mi], b[ni], acc[mi][ni], 0, 0, 0);
    __syncthreads();
  }

  const int rb = rowBlk * 128 + wm * 64 + ((lane >> 4) << 2);
  const int cb = colBlk * 128 + wn * 64 + (lane & 15);
#pragma unroll
  for (int mi = 0; mi < 4; ++mi) {
#pragma unroll
    for (int ni = 0; ni < 4; ++ni) {
      const int coln = cb + ni * 16;
      const float bz = bias[coln];
      const size_t base = (size_t)(rb + mi * 16) * O + coln;
#pragma unroll
      for (int r = 0; r < 4; ++r)
        Cmat[base + (size_t)r * O] = (unsigned short)f2b(acc[mi][ni][r] + bz);
    }
  }
}

// --- BN batch stats over e_out[p] = PR[rows_s[p]] + PC[cols_s[p]] ----------
__global__ __launch_bounds__(256) void edge_stats(
    const unsigned short* __restrict__ PRPC,
    const int* __restrict__ rows_s, const int* __restrict__ cols_s,
    float* __restrict__ sums, float* __restrict__ sumsq) {
  __shared__ float red[8][256];
  const int c8 = threadIdx.x & 31;
  const int sub = threadIdx.x >> 5;
  float s[8], q[8];
#pragma unroll
  for (int j = 0; j < 8; ++j) { s[j] = 0.f; q[j] = 0.f; }
#pragma unroll 1
  for (int grp = 0; grp < 2; ++grp) {
    const int kb = blockIdx.x * 64 + grp * 32 + sub * 4;
    int r[4], cj[4];
#pragma unroll
    for (int u = 0; u < 4; ++u) { r[u] = rows_s[kb + u]; cj[u] = cols_s[kb + u]; }
    uint4 pr[4], pc[4];
#pragma unroll
    for (int u = 0; u < 4; ++u)
      pr[u] = *reinterpret_cast<const uint4*>(PRPC + (size_t)r[u] * 512 + c8 * 8);
#pragma unroll
    for (int u = 0; u < 4; ++u)
      pc[u] = *reinterpret_cast<const uint4*>(PRPC + (size_t)cj[u] * 512 + 256 + c8 * 8);
#pragma unroll
    for (int u = 0; u < 4; ++u) {
      const unsigned int rw[4] = {pr[u].x, pr[u].y, pr[u].z, pr[u].w};
      const unsigned int cw[4] = {pc[u].x, pc[u].y, pc[u].z, pc[u].w};
#pragma unroll
      for (int p4 = 0; p4 < 4; ++p4) {
        const float v0 = lof(rw[p4]) + lof(cw[p4]);
        const float v1 = hif(rw[p4]) + hif(cw[p4]);
        s[2 * p4] += v0;     q[2 * p4] += v0 * v0;
        s[2 * p4 + 1] += v1; q[2 * p4 + 1] += v1 * v1;
      }
    }
  }
#pragma unroll
  for (int j = 0; j < 8; ++j) red[sub][c8 * 8 + j] = s[j];
  __syncthreads();
  {
    const int c = threadIdx.x;
    float t = 0.f;
#pragma unroll
    for (int u2 = 0; u2 < 8; ++u2) t += red[u2][c];
    atomicAdd(sums + c, t);
  }
  __syncthreads();
#pragma unroll
  for (int j = 0; j < 8; ++j) red[sub][c8 * 8 + j] = q[j];
  __syncthreads();
  {
    const int c = threadIdx.x;
    float t = 0.f;
#pragma unroll
    for (int u2 = 0; u2 < 8; ++u2) t += red[u2][c];
    atomicAdd(sumsq + c, t);
  }
}

// --- counting sort of edges by row -----------------------------------------
__global__ __launch_bounds__(256) void hist_rows(const int* __restrict__ ei,
                                                 const int* __restrict__ modep,
                                                 int* __restrict__ cnt, int Nn) {
  const int k = blockIdx.x * 256 + threadIdx.x;
  if (k >= Nn) return;
  const int row = (*modep) ? ei[2 * k] : ei[k];
  atomicAdd(&cnt[row], 1);
}

__global__ __launch_bounds__(256) void scan1(const int* __restrict__ cnt,
                                             int* __restrict__ bsum) {
  __shared__ int red[256];
  const int t = threadIdx.x;
  red[t] = cnt[blockIdx.x * 256 + t];
  __syncthreads();
#pragma unroll
  for (int s = 128; s > 0; s >>= 1) {
    if (t < s) red[t] += red[t + s];
    __syncthreads();
  }
  if (t == 0) bsum[blockIdx.x] = red[0];
}

__global__ __launch_bounds__(512) void scan2(int* __restrict__ bsum, int nb) {
  __shared__ int tmp[512];
  const int t = threadIdx.x;
  const int own = (t < nb) ? bsum[t] : 0;
  tmp[t] = own;
  __syncthreads();
  for (int off = 1; off < 512; off <<= 1) {
    int v = (t >= off) ? tmp[t - off] : 0;
    __syncthreads();
    tmp[t] += v;
    __syncthreads();
  }
  if (t < nb) bsum[t] = tmp[t] - own;  // exclusive
}

__global__ __launch_bounds__(256) void scan3(const int* __restrict__ cnt,
                                             const int* __restrict__ bsum,
                                             int* __restrict__ base, int Nn) {
  __shared__ int tmp[256];
  const int t = threadIdx.x;
  const int gid = blockIdx.x * 256 + t;
  const int own = cnt[gid];
  tmp[t] = own;
  __syncthreads();
  for (int off = 1; off < 256; off <<= 1) {
    int v = (t >= off) ? tmp[t - off] : 0;
    __syncthreads();
    tmp[t] += v;
    __syncthreads();
  }
  base[gid] = tmp[t] - own + bsum[blockIdx.x];
  if (gid == 0) base[Nn] = Nn;  // E == N
}

__global__ __launch_bounds__(256) void scatter_eids(const int* __restrict__ ei,
                                                    const int* __restrict__ modep,
                                                    const int* __restrict__ base,
                                                    int* __restrict__ cnt,
                                                    int* __restrict__ rows_s,
                                                    int* __restrict__ cols_s, int Nn) {
  const int k = blockIdx.x * 256 + threadIdx.x;
  if (k >= Nn) return;
  int row, col;
  if (*modep) { row = ei[2 * k]; col = ei[2 * (Nn + k)]; }
  else        { row = ei[k];     col = ei[Nn + k]; }
  const int pos = base[row] + atomicAdd(&cnt[row], -1) - 1;
  rows_s[pos] = row;
  cols_s[pos] = col;
}

// --- fused: sig[i] = sigmoid(e[i] + sum_seg relu(sc*(PR[i]+PC[col])+sh))
//     accB[i] = bf16(sig); colsum += sig; Traw += sig * HV[col_orig[i]] -----
#define GCAP 1024
__global__ __launch_bounds__(256) void gather_sig_T(
    const float* __restrict__ e, const unsigned short* __restrict__ PRPC,
    const int* __restrict__ base, const int* __restrict__ cols_s,
    const int* __restrict__ ei, const int* __restrict__ modep,
    const unsigned short* __restrict__ VU,
    const float* __restrict__ sums, const float* __restrict__ sumsq,
    const float* __restrict__ gamma, const float* __restrict__ beta,
    unsigned short* __restrict__ accB, float* __restrict__ colsum,
    float* __restrict__ Traw, float invE, int Nn) {
  __shared__ float red[4][256];
  __shared__ int colsL[GCAP];
  __shared__ int baseL[65];
  const int lane = threadIdx.x & 63, w = threadIdx.x >> 6;
  const int n0 = blockIdx.x * 64;
  if (threadIdx.x < 65) baseL[threadIdx.x] = base[n0 + threadIdx.x];
  __syncthreads();
  const int bstart = baseL[0];
  const int bcount = baseL[64] - bstart;
  for (int qq = threadIdx.x; qq < bcount && qq < GCAP; qq += 256)
    colsL[qq] = cols_s[bstart + qq];
  // per-lane BN scale/shift for channels lane*4..lane*4+3
  const float4 sm = *reinterpret_cast<const float4*>(sums + lane * 4);
  const float4 sq = *reinterpret_cast<const float4*>(sumsq + lane * 4);
  const float4 gm = *reinterpret_cast<const float4*>(gamma + lane * 4);
  const float4 bt = *reinterpret_cast<const float4*>(beta + lane * 4);
  float4 sc, sh;
  {
    const float mx = sm.x * invE, my = sm.y * invE, mz = sm.z * invE, mw = sm.w * invE;
    sc.x = gm.x * rsqrtf(fmaxf(sq.x * invE - mx * mx, 0.f) + 1e-5f);
    sc.y = gm.y * rsqrtf(fmaxf(sq.y * invE - my * my, 0.f) + 1e-5f);
    sc.z = gm.z * rsqrtf(fmaxf(sq.z * invE - mz * mz, 0.f) + 1e-5f);
    sc.w = gm.w * rsqrtf(fmaxf(sq.w * invE - mw * mw, 0.f) + 1e-5f);
    sh.x = bt.x - mx * sc.x; sh.y = bt.y - my * sc.y;
    sh.z = bt.z - mz * sc.z; sh.w = bt.w - mw * sc.w;
  }
  __syncthreads();
  const int mode = *modep;
  float s0 = 0.f, s1 = 0.f, s2 = 0.f, s3 = 0.f;
  float t0 = 0.f, t1 = 0.f, t2 = 0.f, t3 = 0.f;
  const int i0 = n0 + w * 16;
  int p = baseL[w * 16];
  const int pendW = baseL[w * 16 + 16];
  uint2 pcn; pcn.x = 0; pcn.y = 0;
  if (p < pendW) {
    const int q0 = p - bstart;
    const int cj = (q0 < GCAP) ? colsL[q0] : cols_s[p];
    pcn = *reinterpret_cast<const uint2*>(PRPC + (size_t)cj * 512 + 256 + lane * 4);
  }
  float4 ev = *reinterpret_cast<const float4*>(e + (size_t)i0 * 256 + lane * 4);
  uint2 prv = *reinterpret_cast<const uint2*>(PRPC + (size_t)i0 * 512 + lane * 4);
#pragma unroll 1
  for (int it = 0; it < 16; ++it) {
    const int i = i0 + it;
    // T-path gather (original edge order): issue early, consume at bottom
    const int colT = mode ? ei[2 * (Nn + i)] : ei[Nn + i];
    const uint2 hv = *reinterpret_cast<const uint2*>(VU + (size_t)colT * 512 + lane * 4);
    float4 v = ev;
    const uint2 pr = prv;
    if (it + 1 < 16) {
      ev = *reinterpret_cast<const float4*>(e + (size_t)(i + 1) * 256 + lane * 4);
      prv = *reinterpret_cast<const uint2*>(PRPC + (size_t)(i + 1) * 512 + lane * 4);
    }
    const float pr0 = lof(pr.x), pr1 = hif(pr.x), pr2 = lof(pr.y), pr3 = hif(pr.y);
    const int pe = baseL[w * 16 + it + 1];
#pragma unroll 1
    while (p < pe) {
      const uint2 pc = pcn;
      if (p + 1 < pendW) {
        const int qn = p + 1 - bstart;
        const int cj = (qn < GCAP) ? colsL[qn] : cols_s[p + 1];
        pcn = *reinterpret_cast<const uint2*>(PRPC + (size_t)cj * 512 + 256 + lane * 4);
      }
      v.x += fmaxf(fmaf(sc.x, pr0 + lof(pc.x), sh.x), 0.f);
      v.y += fmaxf(fmaf(sc.y, pr1 + hif(pc.x), sh.y), 0.f);
      v.z += fmaxf(fmaf(sc.z, pr2 + lof(pc.y), sh.z), 0.f);
      v.w += fmaxf(fmaf(sc.w, pr3 + hif(pc.y), sh.w), 0.f);
      ++p;
    }
    v.x = 1.f / (1.f + __expf(-v.x));
    v.y = 1.f / (1.f + __expf(-v.y));
    v.z = 1.f / (1.f + __expf(-v.z));
    v.w = 1.f / (1.f + __expf(-v.w));
    uint2 ob;
    ob.x = f2b(v.x) | (f2b(v.y) << 16);
    ob.y = f2b(v.z) | (f2b(v.w) << 16);
    *reinterpret_cast<uint2*>(accB + (size_t)i * 256 + lane * 4) = ob;
    s0 += v.x; s1 += v.y; s2 += v.z; s3 += v.w;
    t0 += v.x * lof(hv.x); t1 += v.y * hif(hv.x);
    t2 += v.z * lof(hv.y); t3 += v.w * hif(hv.y);
  }
  red[w][lane * 4 + 0] = s0;
  red[w][lane * 4 + 1] = s1;
  red[w][lane * 4 + 2] = s2;
  red[w][lane * 4 + 3] = s3;
  __syncthreads();
  {
    const int c = threadIdx.x;
    atomicAdd(colsum + c, red[0][c] + red[1][c] + red[2][c] + red[3][c]);
  }
  __syncthreads();
  red[w][lane * 4 + 0] = t0;
  red[w][lane * 4 + 1] = t1;
  red[w][lane * 4 + 2] = t2;
  red[w][lane * 4 + 3] = t3;
  __syncthreads();
  {
    const int c = threadIdx.x;
    atomicAdd(Traw + c, red[0][c] + red[1][c] + red[2][c] + red[3][c]);
  }
}

// --- finalize: outE[i] = accB[i]*iv ; outH[i] = relu(HU[i] + iv*Traw) ------
__global__ __launch_bounds__(256) void finalize(
    const unsigned short* __restrict__ accB, const unsigned short* __restrict__ VU,
    const float* __restrict__ colsum, const float* __restrict__ Traw,
    float* __restrict__ outE, float* __restrict__ outH, int nChunks) {
  const int g = blockIdx.x * 256 + threadIdx.x;
  if (g >= nChunks) return;
  const int i = g >> 5, c8 = g & 31;
  const float4 cs0 = *reinterpret_cast<const float4*>(colsum + c8 * 8);
  const float4 cs1 = *reinterpret_cast<const float4*>(colsum + c8 * 8 + 4);
  const float4 tr0 = *reinterpret_cast<const float4*>(Traw + c8 * 8);
  const float4 tr1 = *reinterpret_cast<const float4*>(Traw + c8 * 8 + 4);
  float iv[8] = {1.f / (cs0.x + 1e-5f), 1.f / (cs0.y + 1e-5f),
                 1.f / (cs0.z + 1e-5f), 1.f / (cs0.w + 1e-5f),
                 1.f / (cs1.x + 1e-5f), 1.f / (cs1.y + 1e-5f),
                 1.f / (cs1.z + 1e-5f), 1.f / (cs1.w + 1e-5f)};
  float tt[8] = {tr0.x * iv[0], tr0.y * iv[1], tr0.z * iv[2], tr0.w * iv[3],
                 tr1.x * iv[4], tr1.y * iv[5], tr1.z * iv[6], tr1.w * iv[7]};
  const uint4 sb = *reinterpret_cast<const uint4*>(accB + (size_t)i * 256 + c8 * 8);
  const unsigned int sw[4] = {sb.x, sb.y, sb.z, sb.w};
  float4 e0, e1;
  e0.x = lof(sw[0]) * iv[0]; e0.y = hif(sw[0]) * iv[1];
  e0.z = lof(sw[1]) * iv[2]; e0.w = hif(sw[1]) * iv[3];
  e1.x = lof(sw[2]) * iv[4]; e1.y = hif(sw[2]) * iv[5];
  e1.z = lof(sw[3]) * iv[6]; e1.w = hif(sw[3]) * iv[7];
  float4* qe = reinterpret_cast<float4*>(outE + (size_t)i * 256 + c8 * 8);
  qe[0] = e0; qe[1] = e1;
  const uint4 hu = *reinterpret_cast<const uint4*>(VU + (size_t)i * 512 + 256 + c8 * 8);
  float4 o0, o1;
  o0.x = fmaxf(lof(hu.x) + tt[0], 0.f);
  o0.y = fmaxf(hif(hu.x) + tt[1], 0.f);
  o0.z = fmaxf(lof(hu.y) + tt[2], 0.f);
  o0.w = fmaxf(hif(hu.y) + tt[3], 0.f);
  o1.x = fmaxf(lof(hu.z) + tt[4], 0.f);
  o1.y = fmaxf(hif(hu.z) + tt[5], 0.f);
  o1.z = fmaxf(lof(hu.w) + tt[6], 0.f);
  o1.w = fmaxf(hif(hu.w) + tt[7], 0.f);
  float4* qh = reinterpret_cast<float4*>(outH + (size_t)i * 256 + c8 * 8);
  qh[0] = o0; qh[1] = o1;
}

extern "C" void kernel_launch(void* const* d_in, const int* in_sizes, int n_in,
                              void* d_out, int out_size, void* d_ws, size_t ws_size,
                              hipStream_t stream) {
  const float* h     = (const float*)d_in[0];
  const int*   ei    = (const int*)d_in[1];
  const float* e     = (const float*)d_in[2];
  const float* Aw    = (const float*)d_in[3];
  const float* Ab    = (const float*)d_in[4];
  const float* Bw    = (const float*)d_in[5];
  const float* Bb    = (const float*)d_in[6];
  const float* Cw    = (const float*)d_in[7];
  const float* Cb    = (const float*)d_in[8];
  const float* Dw    = (const float*)d_in[9];
  const float* Db    = (const float*)d_in[10];
  const float* gamma = (const float*)d_in[11];
  const float* beta  = (const float*)d_in[12];
  const float* Uw    = (const float*)d_in[13];
  const float* Ub    = (const float*)d_in[14];
  const float* Vw    = (const float*)d_in[15];
  const float* Vb    = (const float*)d_in[16];
  const int N = in_sizes[0] / 256;  // 131072

  char* ws = (char*)d_ws;
  unsigned short* W1h = (unsigned short*)(ws + 0x0);       // [A;B] tiled, 256 KiB
  unsigned short* W1e = (unsigned short*)(ws + 0x40000);   // [D;C] tiled, 256 KiB
  unsigned short* W2t = (unsigned short*)(ws + 0x80000);   // [V;U] tiled, 256 KiB
  float* b1     = (float*)(ws + 0xC0000);
  float* b2     = (float*)(ws + 0xC0800);
  float* sums   = (float*)(ws + 0xC1000);
  float* sumsq  = (float*)(ws + 0xC1400);
  float* colsum = (float*)(ws + 0xC1800);
  float* Traw   = (float*)(ws + 0xC1C00);
  int*   mode   = (int*)(ws + 0xC2C00);
  unsigned short* h_t  = (unsigned short*)(ws + 0x100000);   // 64 MiB
  unsigned short* e_t  = (unsigned short*)(ws + 0x4100000);  // 64 MiB
  unsigned short* PRPC = (unsigned short*)(ws + 0x8100000);  // 128 MiB
  unsigned short* VU   = (unsigned short*)(ws + 0x10100000); // 128 MiB
  unsigned short* accB = (unsigned short*)(ws + 0x100000);   // overlays h_t (dead after GEMM2)
  int* cnt    = (int*)(ws + 0x18100000);
  int* baseA  = (int*)(ws + 0x18180000);
  int* rows_s = (int*)(ws + 0x18210000);
  int* cols_s = (int*)(ws + 0x18290000);
  int* bsum   = (int*)(ws + 0x18310000);

  float* outH = (float*)d_out;
  float* outE = outH + (size_t)N * 256;

  hipMemsetAsync(ws + 0xC1000, 0, 4096, stream);   // sums,sumsq,colsum,Traw
  hipMemsetAsync(cnt, 0, (size_t)N * 4, stream);
  prep_weights<<<192, 256, 0, stream>>>(Aw, Bw, Dw, Cw, Vw, Uw, W1h, W1e, W2t,
                                        Ab, Db, Bb, Cb, Vb, Ub, b1, b2, ei, mode);

  // counting sort of edges by row
  hist_rows<<<N / 256, 256, 0, stream>>>(ei, mode, cnt, N);
  scan1<<<N / 256, 256, 0, stream>>>(cnt, bsum);          // 512 blocks @ N=131072
  scan2<<<1, 512, 0, stream>>>(bsum, N / 256);            // nb = 512
  scan3<<<N / 256, 256, 0, stream>>>(cnt, bsum, baseA, N);
  scatter_eids<<<N / 256, 256, 0, stream>>>(ei, mode, baseA, cnt, rows_s, cols_s, N);

  const int nChunks = N * 32;
  prep_he<<<2 * nChunks / 256, 256, 0, stream>>>(h, h_t, e, e_t, nChunks);
  // GEMM1: PRPC = [h|e] @ [[A|D];[B|C]]^T + b1   (O=512, K=512)
  gemm_bt2<<<(N / 128) * 4, 256, 0, stream>>>(h_t, e_t, W1h, W1e, b1, PRPC, 512, 4, 16, (N / 128) * 4);
  // GEMM2: VU = h @ [V;U]^T + b2                 (O=512, K=256)
  gemm_bt2<<<(N / 128) * 4, 256, 0, stream>>>(h_t, h_t, W2t, W2t, b2, VU, 512, 4, 8, (N / 128) * 4);

  edge_stats<<<N / 64, 256, 0, stream>>>(PRPC, rows_s, cols_s, sums, sumsq);
  gather_sig_T<<<N / 64, 256, 0, stream>>>(e, PRPC, baseA, cols_s, ei, mode, VU,
                                           sums, sumsq, gamma, beta,
                                           accB, colsum, Traw, 1.0f / (float)N, N);
  finalize<<<nChunks / 256, 256, 0, stream>>>(accB, VU, colsum, Traw, outE, outH, nChunks);
}